// Round 2
// baseline (3457.856 us; speedup 1.0000x reference)
//
#include <hip/hip_runtime.h>
#include <math.h>

#define TT 16
#define HH 112
#define WD 112
#define CC 96
#define NHEADS 3
#define HD 32
#define NN 98          // window tokens 2*7*7
#define NWIN 2048      // 8*16*16
#define NTOK 200704    // T*H*W == NWIN*NN
#define MLPH 384
#define SXLD 100       // sX row stride in bf16 elems (50 dwords, 2-way conflict = free)

typedef unsigned int  u32;
typedef unsigned short u16;

__device__ inline u16 f2bf(float f) {
  u32 u = __float_as_uint(f);
  u += 0x7fffu + ((u >> 16) & 1u);
  return (u16)(u >> 16);
}
__device__ inline float bflo(u32 u) { return __uint_as_float(u << 16); }
__device__ inline float bfhi(u32 u) { return __uint_as_float(u & 0xffff0000u); }

// ---------------- K0: bias table biasT[head][m][n] = rpb[ridx(n,m)*3+head] ----------------
__global__ __launch_bounds__(256) void bias_kernel(const float* __restrict__ rpb,
                                                   float* __restrict__ biasT) {
  int idx = blockIdx.x * 256 + threadIdx.x;
  if (idx >= NHEADS * NN * NN) return;
  int head = idx / (NN * NN);
  int r = idx - head * NN * NN;
  int m = r / NN, n = r - m * NN;         // n = query row, m = key
  int itn = n / 49, rn = n - itn * 49, ihn = rn / 7, iwn = rn - ihn * 7;
  int itm = m / 49, rm = m - itm * 49, ihm = rm / 7, iwm = rm - ihm * 7;
  int ridx = (itn - itm + 1) * 169 + (ihn - ihm + 6) * 13 + (iwn - iwm + 6);
  biasT[idx] = rpb[ridx * NHEADS + head];
}

// ---------------- K1: LN1 + shifted window gather + QKV + attention (all heads) ----------------
__global__ __launch_bounds__(384) void attn_kernel(
    const float* __restrict__ x, const float* __restrict__ g1, const float* __restrict__ b1,
    const float* __restrict__ qkv_w, const float* __restrict__ qkv_b,
    const float* __restrict__ biasT, u16* __restrict__ att)
{
  __shared__ u16 sX[NN * SXLD];     // 19600 B  (bf16, post-LN)
  __shared__ u16 sKV[NN * 192];     // 37632 B  (K cols 0..95 = qkv cols 96..191; V cols 96..191 = qkv 192..287)
  __shared__ int sReg[NN];

  const int tid  = threadIdx.x;
  const int widx = blockIdx.x;
  const int ww = widx & 15, hw = (widx >> 4) & 15, tw = widx >> 8;

  // phase 1: gather rolled window -> bf16 LDS
  for (int e = tid; e < NN * CC; e += 384) {
    int n = e / CC, c = e - n * CC;
    int it = n / 49, r = n - it * 49, ih = r / 7, iw = r - ih * 7;
    int t = tw * 2 + it + 1; if (t >= TT) t -= TT;
    int h = hw * 7 + ih + 3; if (h >= HH) h -= HH;
    int w = ww * 7 + iw + 3; if (w >= WD) w -= WD;
    sX[n * SXLD + c] = f2bf(x[((size_t)(t * HH + h) * WD + w) * CC + c]);
  }
  if (tid < NN) {
    int n = tid;
    int it = n / 49, r = n - it * 49, ih = r / 7, iw = r - ih * 7;
    int ts = tw * 2 + it, hs = hw * 7 + ih, ws2 = ww * 7 + iw;
    int rt = ts < TT - 2 ? 0 : (ts < TT - 1 ? 1 : 2);
    int rh = hs < HH - 7 ? 0 : (hs < HH - 3 ? 1 : 2);
    int rw = ws2 < WD - 7 ? 0 : (ws2 < WD - 3 ? 1 : 2);
    sReg[n] = rt * 9 + rh * 3 + rw;
  }
  __syncthreads();

  // phase 2: LayerNorm per token, in place (98 lanes; stride-100 bf16 -> 2-way bank alias, free)
  if (tid < NN) {
    u16* row = &sX[tid * SXLD];
    float mu = 0.f;
    for (int c = 0; c < CC; c += 2) { u32 u = *(const u32*)(row + c); mu += bflo(u) + bfhi(u); }
    mu *= (1.f / CC);
    float var = 0.f;
    for (int c = 0; c < CC; c += 2) {
      u32 u = *(const u32*)(row + c);
      float d0 = bflo(u) - mu, d1 = bfhi(u) - mu;
      var += d0 * d0 + d1 * d1;
    }
    var *= (1.f / CC);
    float inv = rsqrtf(var + 1e-5f);
    for (int c = 0; c < CC; ++c) {
      float v = bflo(((u32)row[c]) << 0) ; // placeholder avoided below
      v = __uint_as_float(((u32)row[c]) << 16);
      row[c] = f2bf((v - mu) * inv * g1[c] + b1[c]);
    }
  }
  __syncthreads();

  // phase 3: K and V for all heads (qkv cols 96..287) -> bf16 LDS
  for (int e = tid; e < NN * 192; e += 384) {
    int n = e / 192, col = e - n * 192;        // col 0..191 -> qkv col 96+col
    int qcol = 96 + col;
    float a = qkv_b[qcol];
    const u16* xr = &sX[n * SXLD];
    const float* wp = &qkv_w[qcol];
    for (int c = 0; c < CC; c += 2) {
      u32 u = *(const u32*)(xr + c);
      a = fmaf(bflo(u), wp[c * (3 * CC)], a);
      a = fmaf(bfhi(u), wp[(c + 1) * (3 * CC)], a);
    }
    sKV[n * 192 + col] = f2bf(a);
  }

  // phase 4: per-task q into registers (task = head*98 + row; 294 tasks)
  const int task = tid;
  const int head = task / NN;
  const int n    = task - head * NN;
  float qreg[HD];
  if (task < NHEADS * NN) {
    #pragma unroll
    for (int d = 0; d < HD; ++d) qreg[d] = qkv_b[head * HD + d];
    const u16* xr = &sX[n * SXLD];
    const int hb = head * HD;
    for (int c = 0; c < CC; c += 2) {
      u32 u = *(const u32*)(xr + c);
      float xlo = bflo(u), xhi = bfhi(u);
      const float* w0 = &qkv_w[c * (3 * CC) + hb];
      const float* w1 = w0 + 3 * CC;
      #pragma unroll
      for (int d = 0; d < HD; ++d) qreg[d] = fmaf(xlo, w0[d], fmaf(xhi, w1[d], qreg[d]));
    }
    const float scale = 0.17677669529663687f;
    #pragma unroll
    for (int d = 0; d < HD; ++d) qreg[d] *= scale;
  }
  __syncthreads();

  // phase 5: online softmax + PV
  if (task < NHEADS * NN) {
    const int regn = sReg[n];
    const float* brow = &biasT[head * NN * NN + n];   // biasT[head][m][n], read +m*98
    float mx = -1e30f, sum = 0.f;
    float acc[HD];
    #pragma unroll
    for (int d = 0; d < HD; ++d) acc[d] = 0.f;

    for (int m = 0; m < NN; ++m) {
      const u16* kr = &sKV[m * 192 + head * HD];
      float s = 0.f;
      #pragma unroll
      for (int p = 0; p < HD / 8; ++p) {
        uint4 u = *(const uint4*)(kr + p * 8);
        s = fmaf(qreg[p*8+0], bflo(u.x), s); s = fmaf(qreg[p*8+1], bfhi(u.x), s);
        s = fmaf(qreg[p*8+2], bflo(u.y), s); s = fmaf(qreg[p*8+3], bfhi(u.y), s);
        s = fmaf(qreg[p*8+4], bflo(u.z), s); s = fmaf(qreg[p*8+5], bfhi(u.z), s);
        s = fmaf(qreg[p*8+6], bflo(u.w), s); s = fmaf(qreg[p*8+7], bfhi(u.w), s);
      }
      s += brow[m * NN];
      if (regn != sReg[m]) s -= 100.f;
      if (s > mx) {
        float rsc = __expf(mx - s);
        sum *= rsc;
        #pragma unroll
        for (int d = 0; d < HD; ++d) acc[d] *= rsc;
        mx = s;
      }
      float p = __expf(s - mx);
      sum += p;
      const u16* vr = &sKV[m * 192 + 96 + head * HD];
      #pragma unroll
      for (int pq = 0; pq < HD / 8; ++pq) {
        uint4 u = *(const uint4*)(vr + pq * 8);
        acc[pq*8+0] = fmaf(p, bflo(u.x), acc[pq*8+0]); acc[pq*8+1] = fmaf(p, bfhi(u.x), acc[pq*8+1]);
        acc[pq*8+2] = fmaf(p, bflo(u.y), acc[pq*8+2]); acc[pq*8+3] = fmaf(p, bfhi(u.y), acc[pq*8+3]);
        acc[pq*8+4] = fmaf(p, bflo(u.z), acc[pq*8+4]); acc[pq*8+5] = fmaf(p, bfhi(u.z), acc[pq*8+5]);
        acc[pq*8+6] = fmaf(p, bflo(u.w), acc[pq*8+6]); acc[pq*8+7] = fmaf(p, bfhi(u.w), acc[pq*8+7]);
      }
    }
    float inv = 1.f / sum;
    // pack 32 bf16 -> 16 dwords, store as 4x uint4
    size_t pos = (size_t)(widx * NN + n) * CC + head * HD;   // even
    u32* dst = (u32*)(att + pos);
    #pragma unroll
    for (int p = 0; p < 4; ++p) {
      uint4 o;
      o.x = (u32)f2bf(acc[p*8+0] * inv) | ((u32)f2bf(acc[p*8+1] * inv) << 16);
      o.y = (u32)f2bf(acc[p*8+2] * inv) | ((u32)f2bf(acc[p*8+3] * inv) << 16);
      o.z = (u32)f2bf(acc[p*8+4] * inv) | ((u32)f2bf(acc[p*8+5] * inv) << 16);
      o.w = (u32)f2bf(acc[p*8+6] * inv) | ((u32)f2bf(acc[p*8+7] * inv) << 16);
      *(uint4*)(dst + p * 4) = o;
    }
  }
}

// ---------------- K2: proj + reverse window + un-roll + shortcut residual ----------------
__global__ __launch_bounds__(256) void proj_kernel(
    const u16* __restrict__ att, const float* __restrict__ proj_w, const float* __restrict__ proj_b,
    const float* __restrict__ x, float* __restrict__ x1)
{
  __shared__ float sA[8 * CC];
  const int tid = threadIdx.x;
  const int base = blockIdx.x * 8;    // window-token index
  for (int e = tid; e < 8 * CC / 2; e += 256) {
    u32 u = ((const u32*)att)[(size_t)base * (CC / 2) + e];
    sA[2 * e] = bflo(u);
    sA[2 * e + 1] = bfhi(u);
  }
  __syncthreads();
  for (int e = tid; e < 8 * CC; e += 256) {
    int lt = e / CC, c = e - lt * CC;
    float a = proj_b[c];
    const float* ar = &sA[lt * CC];
    for (int j = 0; j < CC; ++j) a = fmaf(ar[j], proj_w[j * CC + c], a);
    int tok = base + lt;
    int widx = tok / NN, n = tok - widx * NN;
    int ww = widx & 15, hw = (widx >> 4) & 15, tw = widx >> 8;
    int it = n / 49, r = n - it * 49, ih = r / 7, iw = r - ih * 7;
    int t = tw * 2 + it + 1; if (t >= TT) t -= TT;
    int h = hw * 7 + ih + 3; if (h >= HH) h -= HH;
    int w = ww * 7 + iw + 3; if (w >= WD) w -= WD;
    size_t off = ((size_t)(t * HH + h) * WD + w) * CC + c;
    x1[off] = x[off] + a;
  }
}

// ---------------- K3: LN2 + FC1 + exact GELU + FC2 + residual ----------------
#define MTOK 16
__global__ __launch_bounds__(384) void mlp_kernel(
    const float* __restrict__ x1, const float* __restrict__ g2, const float* __restrict__ b2,
    const float* __restrict__ fc1_w, const float* __restrict__ fc1_b,
    const float* __restrict__ fc2_w, const float* __restrict__ fc2_b,
    float* __restrict__ out)
{
  __shared__ float sRow[MTOK * CC];
  __shared__ float sXn[MTOK * CC];
  __shared__ float sH[MTOK * MLPH];
  __shared__ float sMu[MTOK], sInv[MTOK];
  const int tid = threadIdx.x;
  const size_t base = (size_t)blockIdx.x * MTOK;

  for (int e = tid; e < MTOK * CC; e += 384) sRow[e] = x1[base * CC + e];
  __syncthreads();

  if (tid < MTOK) {
    float mu = 0.f;
    for (int c = 0; c < CC; ++c) mu += sRow[tid * CC + c];
    mu *= (1.f / CC);
    float var = 0.f;
    for (int c = 0; c < CC; ++c) { float d = sRow[tid * CC + c] - mu; var += d * d; }
    var *= (1.f / CC);
    sMu[tid] = mu;
    sInv[tid] = rsqrtf(var + 1e-5f);
  }
  __syncthreads();

  for (int e = tid; e < MTOK * CC; e += 384) {
    int t2 = e / CC, c = e - t2 * CC;
    sXn[e] = (sRow[e] - sMu[t2]) * sInv[t2] * g2[c] + b2[c];
  }
  __syncthreads();

  // FC1 + GELU: thread = hidden unit j
  {
    float acc[MTOK];
    #pragma unroll
    for (int t = 0; t < MTOK; ++t) acc[t] = 0.f;
    for (int c = 0; c < CC; ++c) {
      float wv = fc1_w[c * MLPH + tid];
      #pragma unroll
      for (int t = 0; t < MTOK; ++t) acc[t] = fmaf(sXn[t * CC + c], wv, acc[t]);
    }
    float bj = fc1_b[tid];
    #pragma unroll
    for (int t = 0; t < MTOK; ++t) {
      float v = acc[t] + bj;
      sH[t * MLPH + tid] = 0.5f * v * (1.f + erff(v * 0.70710678118654752f));
    }
  }
  __syncthreads();

  // FC2 + residual: c = tid % 96, token group = tid / 96 (4 tokens each)
  {
    int c = tid % CC, grp = tid / CC;
    float acc[4] = {0.f, 0.f, 0.f, 0.f};
    for (int j = 0; j < MLPH; ++j) {
      float wv = fc2_w[j * CC + c];
      #pragma unroll
      for (int t = 0; t < 4; ++t) acc[t] = fmaf(sH[(grp * 4 + t) * MLPH + j], wv, acc[t]);
    }
    float bc = fc2_b[c];
    #pragma unroll
    for (int t = 0; t < 4; ++t) {
      int tt = grp * 4 + t;
      out[(base + tt) * CC + c] = sRow[tt * CC + c] + acc[t] + bc;
    }
  }
}

extern "C" void kernel_launch(void* const* d_in, const int* in_sizes, int n_in,
                              void* d_out, int out_size, void* d_ws, size_t ws_size,
                              hipStream_t stream) {
  const float* x      = (const float*)d_in[0];
  const float* g1     = (const float*)d_in[1];
  const float* b1     = (const float*)d_in[2];
  const float* qkv_w  = (const float*)d_in[3];
  const float* qkv_b  = (const float*)d_in[4];
  const float* rpb    = (const float*)d_in[5];
  const float* proj_w = (const float*)d_in[6];
  const float* proj_b = (const float*)d_in[7];
  const float* g2     = (const float*)d_in[8];
  const float* b2     = (const float*)d_in[9];
  const float* fc1_w  = (const float*)d_in[10];
  const float* fc1_b  = (const float*)d_in[11];
  const float* fc2_w  = (const float*)d_in[12];
  const float* fc2_b  = (const float*)d_in[13];

  u16*   att   = (u16*)d_ws;                                   // NTOK*96 bf16 = 38.5 MB
  float* x1    = (float*)((char*)d_ws + (size_t)NTOK * CC * 2); // NTOK*96 f32 = 77 MB
  float* biasT = (float*)((char*)x1 + (size_t)NTOK * CC * 4);   // 3*98*98 f32

  bias_kernel<<<(NHEADS * NN * NN + 255) / 256, 256, 0, stream>>>(rpb, biasT);
  attn_kernel<<<NWIN, 384, 0, stream>>>(x, g1, b1, qkv_w, qkv_b, biasT, att);
  proj_kernel<<<NTOK / 8, 256, 0, stream>>>(att, proj_w, proj_b, x, x1);
  mlp_kernel<<<NTOK / MTOK, 384, 0, stream>>>(x1, g2, b2, fc1_w, fc1_b, fc2_w, fc2_b, (float*)d_out);
}

// Round 3
// 1553.203 us; speedup vs baseline: 2.2263x; 2.2263x over previous
//
#include <hip/hip_runtime.h>
#include <math.h>

#define TT 16
#define HH 112
#define WD 112
#define CC 96
#define NHEADS 3
#define HD 32
#define NN 98          // window tokens 2*7*7
#define NWIN 2048      // 8*16*16
#define NTOK 200704    // T*H*W == NWIN*NN
#define MLPH 384
#define SXP 104        // row stride (bf16) for sXn/sQ/sK: 208B rows, 16B-aligned, 2-way bank alias (free)
#define SVP 136        // row stride (bf16) for sVt/sP: 272B rows, 16B-aligned

typedef unsigned int  u32;
typedef unsigned short u16;
typedef float f32x4 __attribute__((ext_vector_type(4)));
typedef short bf16x8 __attribute__((ext_vector_type(8)));

__device__ inline u16 f2bf(float f) {
  u32 u = __float_as_uint(f);
  u += 0x7fffu + ((u >> 16) & 1u);
  return (u16)(u >> 16);
}
__device__ inline float bflo(u32 u) { return __uint_as_float(u << 16); }
__device__ inline float bfhi(u32 u) { return __uint_as_float(u & 0xffff0000u); }

#define MFMA16(a, b, c) __builtin_amdgcn_mfma_f32_16x16x32_bf16((a), (b), (c), 0, 0, 0)

// ---------------- K0a: qkv_wT[col][c] = bf16(qkv_w[c][col]) ----------------
__global__ __launch_bounds__(256) void wprep_kernel(const float* __restrict__ qkv_w,
                                                    u16* __restrict__ qkv_wT) {
  int idx = blockIdx.x * 256 + threadIdx.x;
  if (idx >= 3 * CC * CC) return;
  int col = idx / CC, c = idx - col * CC;
  qkv_wT[col * CC + c] = f2bf(qkv_w[c * (3 * CC) + col]);
}

// ---------------- K0b: biasT[head][q][kv] = rpb[ridx(q,kv)*3+head] ----------------
__global__ __launch_bounds__(256) void bias_kernel(const float* __restrict__ rpb,
                                                   float* __restrict__ biasT) {
  int idx = blockIdx.x * 256 + threadIdx.x;
  if (idx >= NHEADS * NN * NN) return;
  int head = idx / (NN * NN);
  int r = idx - head * NN * NN;
  int q = r / NN, kv = r - q * NN;
  int itq = q / 49, rq = q - itq * 49, ihq = rq / 7, iwq = rq - ihq * 7;
  int itk = kv / 49, rk = kv - itk * 49, ihk = rk / 7, iwk = rk - ihk * 7;
  int ridx = (itq - itk + 1) * 169 + (ihq - ihk + 6) * 13 + (iwq - iwk + 6);
  biasT[idx] = rpb[ridx * NHEADS + head];
}

// ---------------- K1: LN1 + shifted window gather + QKV + attention (MFMA) ----------------
__global__ __launch_bounds__(256, 1) void attn_kernel(
    const float* __restrict__ x, const float* __restrict__ g1, const float* __restrict__ b1,
    const u16* __restrict__ qkv_wT, const float* __restrict__ qkv_b,
    const float* __restrict__ biasT, u16* __restrict__ att)
{
  __shared__ u16 sXn[112 * SXP];   // 23296 B  post-LN tokens [tok][c]
  __shared__ u16 sQ [112 * SXP];   // 23296 B  [tok][96] (scaled)
  __shared__ u16 sK [112 * SXP];   // 23296 B  [tok][96]
  __shared__ u16 sVt[ 96 * SVP];   // 26112 B  [hd][kv]  (kv padded to 128, zero)
  __shared__ u16 sP [112 * SVP];   // 30464 B  [q][kv]   softmax probs
  __shared__ int sReg[NN];

  const int tid  = threadIdx.x;
  const int widx = blockIdx.x;
  const int ww = widx & 15, hw = (widx >> 4) & 15, tw = widx >> 8;
  const int wid = tid >> 6;          // wave 0..3
  const int lane = tid & 63;
  const int g  = lane >> 4;          // lane group 0..3
  const int cl = lane & 15;          // col-in-tile

  // ---- phase 0: zero-init LDS (padding rows/cols must be 0, not garbage)
  {
    u32* p;
    p = (u32*)sXn; for (int i = tid; i < 112 * SXP / 2; i += 256) p[i] = 0;
    p = (u32*)sQ;  for (int i = tid; i < 112 * SXP / 2; i += 256) p[i] = 0;
    p = (u32*)sK;  for (int i = tid; i < 112 * SXP / 2; i += 256) p[i] = 0;
    p = (u32*)sVt; for (int i = tid; i <  96 * SVP / 2; i += 256) p[i] = 0;
    p = (u32*)sP;  for (int i = tid; i < 112 * SVP / 2; i += 256) p[i] = 0;
  }
  __syncthreads();

  // ---- phase 1: gather rolled window -> bf16 LDS + region ids
  for (int e = tid; e < NN * CC; e += 256) {
    int n = e / CC, c = e - n * CC;
    int it = n / 49, r = n - it * 49, ih = r / 7, iw = r - ih * 7;
    int t = tw * 2 + it + 1; if (t >= TT) t -= TT;
    int h = hw * 7 + ih + 3; if (h >= HH) h -= HH;
    int w = ww * 7 + iw + 3; if (w >= WD) w -= WD;
    sXn[n * SXP + c] = f2bf(x[((size_t)(t * HH + h) * WD + w) * CC + c]);
  }
  if (tid < NN) {
    int n = tid;
    int it = n / 49, r = n - it * 49, ih = r / 7, iw = r - ih * 7;
    int ts = tw * 2 + it, hs = hw * 7 + ih, ws2 = ww * 7 + iw;
    int rt = ts < TT - 2 ? 0 : (ts < TT - 1 ? 1 : 2);
    int rh = hs < HH - 7 ? 0 : (hs < HH - 3 ? 1 : 2);
    int rw = ws2 < WD - 7 ? 0 : (ws2 < WD - 3 ? 1 : 2);
    sReg[n] = rt * 9 + rh * 3 + rw;
  }
  __syncthreads();

  // ---- phase 2: LayerNorm per token (98 lanes)
  if (tid < NN) {
    u16* row = &sXn[tid * SXP];
    float mu = 0.f;
    for (int c = 0; c < CC; c += 2) { u32 u = *(const u32*)(row + c); mu += bflo(u) + bfhi(u); }
    mu *= (1.f / CC);
    float var = 0.f;
    for (int c = 0; c < CC; c += 2) {
      u32 u = *(const u32*)(row + c);
      float d0 = bflo(u) - mu, d1 = bfhi(u) - mu;
      var += d0 * d0 + d1 * d1;
    }
    var *= (1.f / CC);
    float inv = rsqrtf(var + 1e-5f);
    for (int c = 0; c < CC; ++c) {
      float v = __uint_as_float(((u32)row[c]) << 16);
      row[c] = f2bf((v - mu) * inv * g1[c] + b1[c]);
    }
  }
  __syncthreads();

  // ---- phase 3: QKV = Xn @ W  (MFMA).  n-tiles 0..5 = Q, 6..11 = K, 12..17 = V(->transposed)
  {
    const int ntStart[5] = {0, 5, 10, 14, 18};
    const int s0 = ntStart[wid], s1 = ntStart[wid + 1];
    const float scale = 0.17677669529663687f;   // 32^-0.5
    for (int mt = 0; mt < 7; ++mt) {
      const u16* arow = &sXn[(mt * 16 + cl) * SXP + 8 * g];
      bf16x8 a0 = *(const bf16x8*)(arow);
      bf16x8 a1 = *(const bf16x8*)(arow + 32);
      bf16x8 a2 = *(const bf16x8*)(arow + 64);
      for (int nt = s0; nt < s1; ++nt) {
        const u16* wrow = qkv_wT + (nt * 16 + cl) * CC + 8 * g;
        bf16x8 b0 = *(const bf16x8*)(wrow);
        bf16x8 b1 = *(const bf16x8*)(wrow + 32);
        bf16x8 b2 = *(const bf16x8*)(wrow + 64);
        f32x4 acc = {0.f, 0.f, 0.f, 0.f};
        acc = MFMA16(a0, b0, acc);
        acc = MFMA16(a1, b1, acc);
        acc = MFMA16(a2, b2, acc);
        float bias = qkv_b[nt * 16 + cl];
        #pragma unroll
        for (int r = 0; r < 4; ++r) {
          int row = mt * 16 + 4 * g + r;
          float v = acc[r] + bias;
          if (nt < 6)       sQ[row * SXP + nt * 16 + cl] = f2bf(v * scale);
          else if (nt < 12) sK[row * SXP + (nt - 6) * 16 + cl] = f2bf(v);
          else              sVt[((nt - 12) * 16 + cl) * SVP + row] = f2bf(v);
        }
      }
    }
  }
  __syncthreads();

  // ---- phase 4: per-head QK^T (MFMA) + in-register softmax + PV (MFMA)
  for (int h = 0; h < NHEADS; ++h) {
    // QK^T + softmax: wave w owns m-tiles {w, w+4}
    #pragma unroll
    for (int mi = 0; mi < 2; ++mi) {
      const int mt = wid + mi * 4;
      if (mt < 7) {
        bf16x8 a = *(const bf16x8*)&sQ[(mt * 16 + cl) * SXP + h * 32 + 8 * g];
        float s[7][4];
        #pragma unroll
        for (int nt = 0; nt < 7; ++nt) {
          bf16x8 b = *(const bf16x8*)&sK[(nt * 16 + cl) * SXP + h * 32 + 8 * g];
          f32x4 acc = {0.f, 0.f, 0.f, 0.f};
          acc = MFMA16(a, b, acc);
          #pragma unroll
          for (int r = 0; r < 4; ++r) s[nt][r] = acc[r];
        }
        // bias + mask + pad-col kill
        #pragma unroll
        for (int nt = 0; nt < 7; ++nt) {
          const int kv = nt * 16 + cl;
          #pragma unroll
          for (int r = 0; r < 4; ++r) {
            const int q = mt * 16 + 4 * g + r;
            float v = s[nt][r];
            if (kv < NN) {
              if (q < NN) {
                v += biasT[((h * NN + q)) * NN + kv];
                if (sReg[q] != sReg[kv]) v -= 100.f;
              }
            } else {
              v = -1e30f;
            }
            s[nt][r] = v;
          }
        }
        // row-wise softmax: reduce over 7 in-lane + 16 lanes (xor 1,2,4,8)
        #pragma unroll
        for (int r = 0; r < 4; ++r) {
          float mx = s[0][r];
          #pragma unroll
          for (int nt = 1; nt < 7; ++nt) mx = fmaxf(mx, s[nt][r]);
          #pragma unroll
          for (int d = 1; d < 16; d <<= 1) mx = fmaxf(mx, __shfl_xor(mx, d, 64));
          float sm = 0.f;
          #pragma unroll
          for (int nt = 0; nt < 7; ++nt) { float p = __expf(s[nt][r] - mx); s[nt][r] = p; sm += p; }
          #pragma unroll
          for (int d = 1; d < 16; d <<= 1) sm += __shfl_xor(sm, d, 64);
          float inv = 1.f / sm;
          const int q = mt * 16 + 4 * g + r;
          #pragma unroll
          for (int nt = 0; nt < 7; ++nt)
            sP[q * SVP + nt * 16 + cl] = f2bf(s[nt][r] * inv);
        }
      }
    }
    __syncthreads();

    // PV: 14 tiles (7 m x 2 n), K = 128 (4 k-steps); round-robin over waves
    for (int t = wid; t < 14; t += 4) {
      const int mt = t >> 1, nt = t & 1;
      f32x4 acc = {0.f, 0.f, 0.f, 0.f};
      #pragma unroll
      for (int ks = 0; ks < 4; ++ks) {
        bf16x8 a = *(const bf16x8*)&sP[(mt * 16 + cl) * SVP + ks * 32 + 8 * g];
        bf16x8 b = *(const bf16x8*)&sVt[(nt * 16 + cl) * SVP + ks * 32 + 8 * g];
        acc = MFMA16(a, b, acc);
      }
      #pragma unroll
      for (int r = 0; r < 4; ++r) {
        const int q = mt * 16 + 4 * g + r;
        if (q < NN)
          att[((size_t)widx * NN + q) * CC + h * 32 + nt * 16 + cl] = f2bf(acc[r]);
      }
    }
    __syncthreads();
  }
}

// ---------------- K2: proj + reverse window + un-roll + shortcut residual ----------------
__global__ __launch_bounds__(256) void proj_kernel(
    const u16* __restrict__ att, const float* __restrict__ proj_w, const float* __restrict__ proj_b,
    const float* __restrict__ x, float* __restrict__ x1)
{
  __shared__ float sA[8 * CC];
  const int tid = threadIdx.x;
  const int base = blockIdx.x * 8;    // window-token index
  for (int e = tid; e < 8 * CC / 2; e += 256) {
    u32 u = ((const u32*)att)[(size_t)base * (CC / 2) + e];
    sA[2 * e] = bflo(u);
    sA[2 * e + 1] = bfhi(u);
  }
  __syncthreads();
  for (int e = tid; e < 8 * CC; e += 256) {
    int lt = e / CC, c = e - lt * CC;
    float a = proj_b[c];
    const float* ar = &sA[lt * CC];
    for (int j = 0; j < CC; ++j) a = fmaf(ar[j], proj_w[j * CC + c], a);
    int tok = base + lt;
    int widx = tok / NN, n = tok - widx * NN;
    int ww = widx & 15, hw = (widx >> 4) & 15, tw = widx >> 8;
    int it = n / 49, r = n - it * 49, ih = r / 7, iw = r - ih * 7;
    int t = tw * 2 + it + 1; if (t >= TT) t -= TT;
    int h = hw * 7 + ih + 3; if (h >= HH) h -= HH;
    int w = ww * 7 + iw + 3; if (w >= WD) w -= WD;
    size_t off = ((size_t)(t * HH + h) * WD + w) * CC + c;
    x1[off] = x[off] + a;
  }
}

// ---------------- K3: LN2 + FC1 + exact GELU + FC2 + residual ----------------
#define MTOK 16
__global__ __launch_bounds__(384) void mlp_kernel(
    const float* __restrict__ x1, const float* __restrict__ g2, const float* __restrict__ b2,
    const float* __restrict__ fc1_w, const float* __restrict__ fc1_b,
    const float* __restrict__ fc2_w, const float* __restrict__ fc2_b,
    float* __restrict__ out)
{
  __shared__ float sRow[MTOK * CC];
  __shared__ float sXn[MTOK * CC];
  __shared__ float sH[MTOK * MLPH];
  __shared__ float sMu[MTOK], sInv[MTOK];
  const int tid = threadIdx.x;
  const size_t base = (size_t)blockIdx.x * MTOK;

  for (int e = tid; e < MTOK * CC; e += 384) sRow[e] = x1[base * CC + e];
  __syncthreads();

  if (tid < MTOK) {
    float mu = 0.f;
    for (int c = 0; c < CC; ++c) mu += sRow[tid * CC + c];
    mu *= (1.f / CC);
    float var = 0.f;
    for (int c = 0; c < CC; ++c) { float d = sRow[tid * CC + c] - mu; var += d * d; }
    var *= (1.f / CC);
    sMu[tid] = mu;
    sInv[tid] = rsqrtf(var + 1e-5f);
  }
  __syncthreads();

  for (int e = tid; e < MTOK * CC; e += 384) {
    int t2 = e / CC, c = e - t2 * CC;
    sXn[e] = (sRow[e] - sMu[t2]) * sInv[t2] * g2[c] + b2[c];
  }
  __syncthreads();

  // FC1 + GELU: thread = hidden unit j
  {
    float acc[MTOK];
    #pragma unroll
    for (int t = 0; t < MTOK; ++t) acc[t] = 0.f;
    for (int c = 0; c < CC; ++c) {
      float wv = fc1_w[c * MLPH + tid];
      #pragma unroll
      for (int t = 0; t < MTOK; ++t) acc[t] = fmaf(sXn[t * CC + c], wv, acc[t]);
    }
    float bj = fc1_b[tid];
    #pragma unroll
    for (int t = 0; t < MTOK; ++t) {
      float v = acc[t] + bj;
      sH[t * MLPH + tid] = 0.5f * v * (1.f + erff(v * 0.70710678118654752f));
    }
  }
  __syncthreads();

  // FC2 + residual: c = tid % 96, token group = tid / 96 (4 tokens each)
  {
    int c = tid % CC, grp = tid / CC;
    float acc[4] = {0.f, 0.f, 0.f, 0.f};
    for (int j = 0; j < MLPH; ++j) {
      float wv = fc2_w[j * CC + c];
      #pragma unroll
      for (int t = 0; t < 4; ++t) acc[t] = fmaf(sH[(grp * 4 + t) * MLPH + j], wv, acc[t]);
    }
    float bc = fc2_b[c];
    #pragma unroll
    for (int t = 0; t < 4; ++t) {
      int tt = grp * 4 + t;
      out[(base + tt) * CC + c] = sRow[tt * CC + c] + acc[t] + bc;
    }
  }
}

extern "C" void kernel_launch(void* const* d_in, const int* in_sizes, int n_in,
                              void* d_out, int out_size, void* d_ws, size_t ws_size,
                              hipStream_t stream) {
  const float* x      = (const float*)d_in[0];
  const float* g1     = (const float*)d_in[1];
  const float* b1     = (const float*)d_in[2];
  const float* qkv_w  = (const float*)d_in[3];
  const float* qkv_b  = (const float*)d_in[4];
  const float* rpb    = (const float*)d_in[5];
  const float* proj_w = (const float*)d_in[6];
  const float* proj_b = (const float*)d_in[7];
  const float* g2     = (const float*)d_in[8];
  const float* b2     = (const float*)d_in[9];
  const float* fc1_w  = (const float*)d_in[10];
  const float* fc1_b  = (const float*)d_in[11];
  const float* fc2_w  = (const float*)d_in[12];
  const float* fc2_b  = (const float*)d_in[13];

  char* ws = (char*)d_ws;
  u16*   att    = (u16*)ws;                                   // NTOK*96 bf16 = 38.5 MB
  float* x1     = (float*)(ws + (size_t)NTOK * CC * 2);       // NTOK*96 f32 = 77 MB
  float* biasT  = (float*)(ws + (size_t)NTOK * CC * 6);       // 3*98*98 f32 = 115 KB
  u16*   qkv_wT = (u16*)(ws + (size_t)NTOK * CC * 6 + NHEADS * NN * NN * 4);  // 288*96 bf16

  wprep_kernel<<<(3 * CC * CC + 255) / 256, 256, 0, stream>>>(qkv_w, qkv_wT);
  bias_kernel<<<(NHEADS * NN * NN + 255) / 256, 256, 0, stream>>>(rpb, biasT);
  attn_kernel<<<NWIN, 256, 0, stream>>>(x, g1, b1, qkv_wT, qkv_b, biasT, att);
  proj_kernel<<<NTOK / 8, 256, 0, stream>>>(att, proj_w, proj_b, x, x1);
  mlp_kernel<<<NTOK / MTOK, 384, 0, stream>>>(x1, g2, b2, fc1_w, fc1_b, fc2_w, fc2_b, (float*)d_out);
}

// Round 4
// 823.540 us; speedup vs baseline: 4.1988x; 1.8860x over previous
//
#include <hip/hip_runtime.h>
#include <math.h>

#define TT 16
#define HH 112
#define WD 112
#define CC 96
#define NHEADS 3
#define HD 32
#define NN 98          // window tokens 2*7*7
#define NWIN 2048      // 8*16*16
#define NTOK 200704    // T*H*W == NWIN*NN
#define MLPH 384
#define SXP 104        // row stride (bf16): 52 dwords == 20 mod 32 -> even bank spread with 4g offset
#define SVP 136        // row stride (bf16) for sVt/sP: 68 dwords == 4 mod 32
#define SHP 392        // row stride (bf16) for sH: 196 dwords == 4 mod 32

typedef unsigned int  u32;
typedef unsigned short u16;
typedef float f32x4 __attribute__((ext_vector_type(4)));
typedef short bf16x8 __attribute__((ext_vector_type(8)));

__device__ inline u16 f2bf(float f) {
  u32 u = __float_as_uint(f);
  u += 0x7fffu + ((u >> 16) & 1u);
  return (u16)(u >> 16);
}
__device__ inline float bflo(u32 u) { return __uint_as_float(u << 16); }
__device__ inline float bfhi(u32 u) { return __uint_as_float(u & 0xffff0000u); }

#define MFMA16(a, b, c) __builtin_amdgcn_mfma_f32_16x16x32_bf16((a), (b), (c), 0, 0, 0)

// ---------------- K0a: transpose all weights to bf16 col-major ----------------
__global__ __launch_bounds__(256) void wprep_kernel(
    const float* __restrict__ qkv_w, const float* __restrict__ proj_w,
    const float* __restrict__ fc1_w, const float* __restrict__ fc2_w,
    u16* __restrict__ qkv_wT, u16* __restrict__ proj_wT,
    u16* __restrict__ fc1_wT, u16* __restrict__ fc2_wT) {
  int idx = blockIdx.x * 256 + threadIdx.x;
  if (idx < 27648) {                       // qkv_wT[col][c]
    int col = idx / CC, c = idx - col * CC;
    qkv_wT[idx] = f2bf(qkv_w[c * (3 * CC) + col]);
    return;
  }
  idx -= 27648;
  if (idx < 9216) {                        // proj_wT[col][c]
    int col = idx / CC, c = idx - col * CC;
    proj_wT[idx] = f2bf(proj_w[c * CC + col]);
    return;
  }
  idx -= 9216;
  if (idx < 36864) {                       // fc1_wT[j][c]
    int j = idx / CC, c = idx - j * CC;
    fc1_wT[idx] = f2bf(fc1_w[c * MLPH + j]);
    return;
  }
  idx -= 36864;
  if (idx < 36864) {                       // fc2_wT[c][j]
    int c = idx / MLPH, j = idx - c * MLPH;
    fc2_wT[idx] = f2bf(fc2_w[j * CC + c]);
  }
}

// ---------------- K0b: biasT[head][q][kv] = rpb[ridx(q,kv)*3+head] ----------------
__global__ __launch_bounds__(256) void bias_kernel(const float* __restrict__ rpb,
                                                   float* __restrict__ biasT) {
  int idx = blockIdx.x * 256 + threadIdx.x;
  if (idx >= NHEADS * NN * NN) return;
  int head = idx / (NN * NN);
  int r = idx - head * NN * NN;
  int q = r / NN, kv = r - q * NN;
  int itq = q / 49, rq = q - itq * 49, ihq = rq / 7, iwq = rq - ihq * 7;
  int itk = kv / 49, rk = kv - itk * 49, ihk = rk / 7, iwk = rk - ihk * 7;
  int ridx = (itq - itk + 1) * 169 + (ihq - ihk + 6) * 13 + (iwq - iwk + 6);
  biasT[idx] = rpb[ridx * NHEADS + head];
}

// ---------------- K1: LN1 + shifted window gather + QKV + attention (MFMA) ----------------
__global__ __launch_bounds__(256, 1) void attn_kernel(
    const float* __restrict__ x, const float* __restrict__ g1, const float* __restrict__ b1,
    const u16* __restrict__ qkv_wT, const float* __restrict__ qkv_b,
    const float* __restrict__ biasT, u16* __restrict__ att)
{
  __shared__ u16 sXn[112 * SXP];   // 23296 B  post-LN tokens [tok][c]
  __shared__ u16 sQ [112 * SXP];   // 23296 B  [tok][96] (scaled)
  __shared__ u16 sK [112 * SXP];   // 23296 B  [tok][96]
  __shared__ u16 sVt[ 96 * SVP];   // 26112 B  [hd][kv]  (kv padded to 128, zero)
  __shared__ u16 sP [112 * SVP];   // 30464 B  [q][kv]   softmax probs
  __shared__ int sReg[NN];

  const int tid  = threadIdx.x;
  const int widx = blockIdx.x;
  const int ww = widx & 15, hw = (widx >> 4) & 15, tw = widx >> 8;
  const int wid = tid >> 6;          // wave 0..3
  const int lane = tid & 63;
  const int g  = lane >> 4;          // lane group 0..3
  const int cl = lane & 15;          // col-in-tile

  // ---- phase 0: zero-init LDS (padding rows/cols must be 0, not garbage)
  {
    u32* p;
    p = (u32*)sXn; for (int i = tid; i < 112 * SXP / 2; i += 256) p[i] = 0;
    p = (u32*)sQ;  for (int i = tid; i < 112 * SXP / 2; i += 256) p[i] = 0;
    p = (u32*)sK;  for (int i = tid; i < 112 * SXP / 2; i += 256) p[i] = 0;
    p = (u32*)sVt; for (int i = tid; i <  96 * SVP / 2; i += 256) p[i] = 0;
    p = (u32*)sP;  for (int i = tid; i < 112 * SVP / 2; i += 256) p[i] = 0;
  }
  __syncthreads();

  // ---- phase 1: gather rolled window -> bf16 LDS + region ids
  for (int e = tid; e < NN * CC; e += 256) {
    int n = e / CC, c = e - n * CC;
    int it = n / 49, r = n - it * 49, ih = r / 7, iw = r - ih * 7;
    int t = tw * 2 + it + 1; if (t >= TT) t -= TT;
    int h = hw * 7 + ih + 3; if (h >= HH) h -= HH;
    int w = ww * 7 + iw + 3; if (w >= WD) w -= WD;
    sXn[n * SXP + c] = f2bf(x[((size_t)(t * HH + h) * WD + w) * CC + c]);
  }
  if (tid < NN) {
    int n = tid;
    int it = n / 49, r = n - it * 49, ih = r / 7, iw = r - ih * 7;
    int ts = tw * 2 + it, hs = hw * 7 + ih, ws2 = ww * 7 + iw;
    int rt = ts < TT - 2 ? 0 : (ts < TT - 1 ? 1 : 2);
    int rh = hs < HH - 7 ? 0 : (hs < HH - 3 ? 1 : 2);
    int rw = ws2 < WD - 7 ? 0 : (ws2 < WD - 3 ? 1 : 2);
    sReg[n] = rt * 9 + rh * 3 + rw;
  }
  __syncthreads();

  // ---- phase 2: LayerNorm per token (98 lanes)
  if (tid < NN) {
    u16* row = &sXn[tid * SXP];
    float mu = 0.f;
    for (int c = 0; c < CC; c += 2) { u32 u = *(const u32*)(row + c); mu += bflo(u) + bfhi(u); }
    mu *= (1.f / CC);
    float var = 0.f;
    for (int c = 0; c < CC; c += 2) {
      u32 u = *(const u32*)(row + c);
      float d0 = bflo(u) - mu, d1 = bfhi(u) - mu;
      var += d0 * d0 + d1 * d1;
    }
    var *= (1.f / CC);
    float inv = rsqrtf(var + 1e-5f);
    for (int c = 0; c < CC; ++c) {
      float v = __uint_as_float(((u32)row[c]) << 16);
      row[c] = f2bf((v - mu) * inv * g1[c] + b1[c]);
    }
  }
  __syncthreads();

  // ---- phase 3: QKV = Xn @ W  (MFMA).  n-tiles 0..5 = Q, 6..11 = K, 12..17 = V(->transposed)
  {
    const int ntStart[5] = {0, 5, 10, 14, 18};
    const int s0 = ntStart[wid], s1 = ntStart[wid + 1];
    const float scale = 0.17677669529663687f;   // 32^-0.5
    for (int mt = 0; mt < 7; ++mt) {
      const u16* arow = &sXn[(mt * 16 + cl) * SXP + 8 * g];
      bf16x8 a0 = *(const bf16x8*)(arow);
      bf16x8 a1 = *(const bf16x8*)(arow + 32);
      bf16x8 a2 = *(const bf16x8*)(arow + 64);
      for (int nt = s0; nt < s1; ++nt) {
        const u16* wrow = qkv_wT + (nt * 16 + cl) * CC + 8 * g;
        bf16x8 b0 = *(const bf16x8*)(wrow);
        bf16x8 b1 = *(const bf16x8*)(wrow + 32);
        bf16x8 b2 = *(const bf16x8*)(wrow + 64);
        f32x4 acc = {0.f, 0.f, 0.f, 0.f};
        acc = MFMA16(a0, b0, acc);
        acc = MFMA16(a1, b1, acc);
        acc = MFMA16(a2, b2, acc);
        float bias = qkv_b[nt * 16 + cl];
        #pragma unroll
        for (int r = 0; r < 4; ++r) {
          int row = mt * 16 + 4 * g + r;
          float v = acc[r] + bias;
          if (nt < 6)       sQ[row * SXP + nt * 16 + cl] = f2bf(v * scale);
          else if (nt < 12) sK[row * SXP + (nt - 6) * 16 + cl] = f2bf(v);
          else              sVt[((nt - 12) * 16 + cl) * SVP + row] = f2bf(v);
        }
      }
    }
  }
  __syncthreads();

  // ---- phase 4: per-head QK^T (MFMA) + in-register softmax + PV (MFMA)
  for (int h = 0; h < NHEADS; ++h) {
    // QK^T + softmax: wave w owns m-tiles {w, w+4}
    #pragma unroll
    for (int mi = 0; mi < 2; ++mi) {
      const int mt = wid + mi * 4;
      if (mt < 7) {
        bf16x8 a = *(const bf16x8*)&sQ[(mt * 16 + cl) * SXP + h * 32 + 8 * g];
        float s[7][4];
        #pragma unroll
        for (int nt = 0; nt < 7; ++nt) {
          bf16x8 b = *(const bf16x8*)&sK[(nt * 16 + cl) * SXP + h * 32 + 8 * g];
          f32x4 acc = {0.f, 0.f, 0.f, 0.f};
          acc = MFMA16(a, b, acc);
          #pragma unroll
          for (int r = 0; r < 4; ++r) s[nt][r] = acc[r];
        }
        // bias + mask + pad-col kill
        #pragma unroll
        for (int nt = 0; nt < 7; ++nt) {
          const int kv = nt * 16 + cl;
          #pragma unroll
          for (int r = 0; r < 4; ++r) {
            const int q = mt * 16 + 4 * g + r;
            float v = s[nt][r];
            if (kv < NN) {
              if (q < NN) {
                v += biasT[((h * NN + q)) * NN + kv];
                if (sReg[q] != sReg[kv]) v -= 100.f;
              }
            } else {
              v = -1e30f;
            }
            s[nt][r] = v;
          }
        }
        // row-wise softmax: reduce over 7 in-lane + 16 lanes (xor 1,2,4,8)
        #pragma unroll
        for (int r = 0; r < 4; ++r) {
          float mx = s[0][r];
          #pragma unroll
          for (int nt = 1; nt < 7; ++nt) mx = fmaxf(mx, s[nt][r]);
          #pragma unroll
          for (int d = 1; d < 16; d <<= 1) mx = fmaxf(mx, __shfl_xor(mx, d, 64));
          float sm = 0.f;
          #pragma unroll
          for (int nt = 0; nt < 7; ++nt) { float p = __expf(s[nt][r] - mx); s[nt][r] = p; sm += p; }
          #pragma unroll
          for (int d = 1; d < 16; d <<= 1) sm += __shfl_xor(sm, d, 64);
          float inv = 1.f / sm;
          const int q = mt * 16 + 4 * g + r;
          #pragma unroll
          for (int nt = 0; nt < 7; ++nt)
            sP[q * SVP + nt * 16 + cl] = f2bf(s[nt][r] * inv);
        }
      }
    }
    __syncthreads();

    // PV: 14 tiles (7 m x 2 n), K = 128 (4 k-steps); round-robin over waves
    for (int t = wid; t < 14; t += 4) {
      const int mt = t >> 1, nt = t & 1;
      f32x4 acc = {0.f, 0.f, 0.f, 0.f};
      #pragma unroll
      for (int ks = 0; ks < 4; ++ks) {
        bf16x8 a = *(const bf16x8*)&sP[(mt * 16 + cl) * SVP + ks * 32 + 8 * g];
        bf16x8 b = *(const bf16x8*)&sVt[(nt * 16 + cl) * SVP + ks * 32 + 8 * g];
        acc = MFMA16(a, b, acc);
      }
      #pragma unroll
      for (int r = 0; r < 4; ++r) {
        const int q = mt * 16 + 4 * g + r;
        if (q < NN)
          att[((size_t)widx * NN + q) * CC + h * 32 + nt * 16 + cl] = f2bf(acc[r]);
      }
    }
    __syncthreads();
  }
}

// ---------------- K2: proj (MFMA) + reverse window + un-roll + residual ----------------
__global__ __launch_bounds__(256) void proj_kernel(
    const u16* __restrict__ att, const u16* __restrict__ proj_wT, const float* __restrict__ proj_b,
    const float* __restrict__ x, float* __restrict__ x1)
{
  __shared__ u16 sA[64 * SXP];   // 13312 B
  const int tid = threadIdx.x;
  const int base = blockIdx.x * 64;            // window-token index
  const int wid = tid >> 6, lane = tid & 63, g = lane >> 4, cl = lane & 15;

  // load 64 att rows (bf16, contiguous [tok][96]) -> LDS stride SXP
  for (int e = tid; e < 64 * (CC / 8); e += 256) {
    int tok = e / 12, kb = e - tok * 12;
    *(uint4*)&sA[tok * SXP + kb * 8] =
        ((const uint4*)att)[((size_t)(base + tok) * CC + kb * 8) >> 3];
  }
  __syncthreads();

  // per-lane output rows: token = base + wid*16 + 4g + r  -> global offset of its (t,h,w) row
  size_t rowOff[4];
  #pragma unroll
  for (int r = 0; r < 4; ++r) {
    int tok = base + wid * 16 + 4 * g + r;
    int widx = tok / NN, n = tok - widx * NN;
    int ww = widx & 15, hw = (widx >> 4) & 15, tw = widx >> 8;
    int it = n / 49, rr = n - it * 49, ih = rr / 7, iw = rr - ih * 7;
    int t = tw * 2 + it + 1; if (t >= TT) t -= TT;
    int h = hw * 7 + ih + 3; if (h >= HH) h -= HH;
    int w = ww * 7 + iw + 3; if (w >= WD) w -= WD;
    rowOff[r] = ((size_t)(t * HH + h) * WD + w) * CC;
  }

  const u16* aRow = &sA[(wid * 16 + cl) * SXP + 8 * g];
  bf16x8 a0 = *(const bf16x8*)(aRow);
  bf16x8 a1 = *(const bf16x8*)(aRow + 32);
  bf16x8 a2 = *(const bf16x8*)(aRow + 64);
  for (int nt = 0; nt < 6; ++nt) {
    const u16* bRow = proj_wT + (nt * 16 + cl) * CC + 8 * g;
    f32x4 acc = {0.f, 0.f, 0.f, 0.f};
    acc = MFMA16(a0, *(const bf16x8*)(bRow), acc);
    acc = MFMA16(a1, *(const bf16x8*)(bRow + 32), acc);
    acc = MFMA16(a2, *(const bf16x8*)(bRow + 64), acc);
    float bc = proj_b[nt * 16 + cl];
    #pragma unroll
    for (int r = 0; r < 4; ++r) {
      size_t off = rowOff[r] + nt * 16 + cl;
      x1[off] = x[off] + acc[r] + bc;
    }
  }
}

// ---------------- K3: LN2 + FC1 + exact GELU + FC2 + residual (MFMA) ----------------
__global__ __launch_bounds__(256) void mlp_kernel(
    const float* __restrict__ x1, const float* __restrict__ g2, const float* __restrict__ b2,
    const u16* __restrict__ fc1_wT, const float* __restrict__ fc1_b,
    const u16* __restrict__ fc2_wT, const float* __restrict__ fc2_b,
    float* __restrict__ out)
{
  __shared__ u16 sXn[64 * SXP];   // 13312 B
  __shared__ u16 sH [64 * SHP];   // 50176 B
  const int tid = threadIdx.x;
  const size_t base = (size_t)blockIdx.x * 64;
  const int wid = tid >> 6, lane = tid & 63, g = lane >> 4, cl = lane & 15;

  // ---- LN2: token = tid>>2, quarter = tid&3 (24 channels each); 4-lane shfl reduce
  {
    const int tok = tid >> 2, qd = tid & 3;
    const float* row = x1 + (base + tok) * CC + qd * 24;
    float v[24];
    #pragma unroll
    for (int i = 0; i < 24; i += 4) {
      float4 f = *(const float4*)(row + i);
      v[i] = f.x; v[i + 1] = f.y; v[i + 2] = f.z; v[i + 3] = f.w;
    }
    float sm = 0.f;
    #pragma unroll
    for (int i = 0; i < 24; ++i) sm += v[i];
    sm += __shfl_xor(sm, 1, 64);
    sm += __shfl_xor(sm, 2, 64);
    float mu = sm * (1.f / CC);
    float sq = 0.f;
    #pragma unroll
    for (int i = 0; i < 24; ++i) { float d = v[i] - mu; sq += d * d; }
    sq += __shfl_xor(sq, 1, 64);
    sq += __shfl_xor(sq, 2, 64);
    float inv = rsqrtf(sq * (1.f / CC) + 1e-5f);
    #pragma unroll
    for (int i = 0; i < 24; ++i) {
      int c = qd * 24 + i;
      sXn[tok * SXP + c] = f2bf((v[i] - mu) * inv * g2[c] + b2[c]);
    }
  }
  __syncthreads();

  // ---- GEMM1 [64x96]@[96x384] + GELU -> sH (bf16)
  {
    const u16* aRow = &sXn[(wid * 16 + cl) * SXP + 8 * g];
    bf16x8 a0 = *(const bf16x8*)(aRow);
    bf16x8 a1 = *(const bf16x8*)(aRow + 32);
    bf16x8 a2 = *(const bf16x8*)(aRow + 64);
    for (int nt = 0; nt < 24; ++nt) {
      const u16* bRow = fc1_wT + (nt * 16 + cl) * CC + 8 * g;
      f32x4 acc = {0.f, 0.f, 0.f, 0.f};
      acc = MFMA16(a0, *(const bf16x8*)(bRow), acc);
      acc = MFMA16(a1, *(const bf16x8*)(bRow + 32), acc);
      acc = MFMA16(a2, *(const bf16x8*)(bRow + 64), acc);
      float bj = fc1_b[nt * 16 + cl];
      #pragma unroll
      for (int r = 0; r < 4; ++r) {
        float v = acc[r] + bj;
        v = 0.5f * v * (1.f + erff(v * 0.70710678118654752f));
        sH[(wid * 16 + 4 * g + r) * SHP + nt * 16 + cl] = f2bf(v);
      }
    }
  }
  __syncthreads();

  // ---- GEMM2 [64x384]@[384x96] + residual -> out
  {
    const u16* aBase = &sH[(wid * 16 + cl) * SHP + 8 * g];
    bf16x8 a[12];
    #pragma unroll
    for (int ks = 0; ks < 12; ++ks) a[ks] = *(const bf16x8*)(aBase + 32 * ks);
    for (int nt = 0; nt < 6; ++nt) {
      const u16* bBase = fc2_wT + (nt * 16 + cl) * MLPH + 8 * g;
      f32x4 acc = {0.f, 0.f, 0.f, 0.f};
      #pragma unroll
      for (int ks = 0; ks < 12; ++ks)
        acc = MFMA16(a[ks], *(const bf16x8*)(bBase + 32 * ks), acc);
      float bc = fc2_b[nt * 16 + cl];
      #pragma unroll
      for (int r = 0; r < 4; ++r) {
        size_t off = (base + wid * 16 + 4 * g + r) * CC + nt * 16 + cl;
        out[off] = x1[off] + acc[r] + bc;
      }
    }
  }
}

extern "C" void kernel_launch(void* const* d_in, const int* in_sizes, int n_in,
                              void* d_out, int out_size, void* d_ws, size_t ws_size,
                              hipStream_t stream) {
  const float* x      = (const float*)d_in[0];
  const float* g1     = (const float*)d_in[1];
  const float* b1     = (const float*)d_in[2];
  const float* qkv_w  = (const float*)d_in[3];
  const float* qkv_b  = (const float*)d_in[4];
  const float* rpb    = (const float*)d_in[5];
  const float* proj_w = (const float*)d_in[6];
  const float* proj_b = (const float*)d_in[7];
  const float* g2     = (const float*)d_in[8];
  const float* b2     = (const float*)d_in[9];
  const float* fc1_w  = (const float*)d_in[10];
  const float* fc1_b  = (const float*)d_in[11];
  const float* fc2_w  = (const float*)d_in[12];
  const float* fc2_b  = (const float*)d_in[13];

  char* ws = (char*)d_ws;
  u16*   att    = (u16*)ws;                                   // 38.5 MB
  float* x1     = (float*)(ws + (size_t)NTOK * CC * 2);       // 77 MB
  char*  wtail  = ws + (size_t)NTOK * CC * 6;
  float* biasT  = (float*)wtail;                              // 115248 B
  u16*   qkv_wT = (u16*)(wtail + 115248);                     // 55296 B
  u16*   proj_wT= (u16*)(wtail + 115248 + 55296);             // 18432 B
  u16*   fc1_wT = (u16*)(wtail + 115248 + 55296 + 18432);     // 73728 B
  u16*   fc2_wT = (u16*)(wtail + 115248 + 55296 + 18432 + 73728); // 73728 B

  wprep_kernel<<<(27648 + 9216 + 36864 + 36864 + 255) / 256, 256, 0, stream>>>(
      qkv_w, proj_w, fc1_w, fc2_w, qkv_wT, proj_wT, fc1_wT, fc2_wT);
  bias_kernel<<<(NHEADS * NN * NN + 255) / 256, 256, 0, stream>>>(rpb, biasT);
  attn_kernel<<<NWIN, 256, 0, stream>>>(x, g1, b1, qkv_wT, qkv_b, biasT, att);
  proj_kernel<<<NTOK / 64, 256, 0, stream>>>(att, proj_wT, proj_b, x, x1);
  mlp_kernel<<<NTOK / 64, 256, 0, stream>>>(x1, g2, b2, fc1_wT, fc1_b, fc2_wT, fc2_b, (float*)d_out);
}

// Round 5
// 473.882 us; speedup vs baseline: 7.2969x; 1.7379x over previous
//
#include <hip/hip_runtime.h>
#include <math.h>

#define TT 16
#define HH 112
#define WD 112
#define CC 96
#define NHEADS 3
#define HD 32
#define NN 98          // window tokens 2*7*7
#define NWIN 2048      // 8*16*16
#define NTOK 200704    // T*H*W == NWIN*NN
#define MLPH 384
#define SXP 104        // row stride (bf16) for mlp/proj LDS tiles
#define SQP 40         // row stride (bf16) for per-head sQ/sK (32 cols + 8 pad)
#define SVP 136        // row stride (bf16) for sVt/sP (128 cols + 8 pad)
#define SHP 392        // row stride (bf16) for sH

typedef unsigned int  u32;
typedef unsigned short u16;
typedef float f32x4 __attribute__((ext_vector_type(4)));
typedef short bf16x8 __attribute__((ext_vector_type(8)));

__device__ inline u16 f2bf(float f) {
  u32 u = __float_as_uint(f);
  u += 0x7fffu + ((u >> 16) & 1u);
  return (u16)(u >> 16);
}
__device__ inline float bflo(u32 u) { return __uint_as_float(u << 16); }
__device__ inline float bfhi(u32 u) { return __uint_as_float(u & 0xffff0000u); }

#define MFMA16(a, b, c) __builtin_amdgcn_mfma_f32_16x16x32_bf16((a), (b), (c), 0, 0, 0)

// ---------------- K0a: transpose all weights to bf16 col-major ----------------
__global__ __launch_bounds__(256) void wprep_kernel(
    const float* __restrict__ qkv_w, const float* __restrict__ proj_w,
    const float* __restrict__ fc1_w, const float* __restrict__ fc2_w,
    u16* __restrict__ qkv_wT, u16* __restrict__ proj_wT,
    u16* __restrict__ fc1_wT, u16* __restrict__ fc2_wT) {
  int idx = blockIdx.x * 256 + threadIdx.x;
  if (idx < 27648) {                       // qkv_wT[col][c]
    int col = idx / CC, c = idx - col * CC;
    qkv_wT[idx] = f2bf(qkv_w[c * (3 * CC) + col]);
    return;
  }
  idx -= 27648;
  if (idx < 9216) {                        // proj_wT[col][c]
    int col = idx / CC, c = idx - col * CC;
    proj_wT[idx] = f2bf(proj_w[c * CC + col]);
    return;
  }
  idx -= 9216;
  if (idx < 36864) {                       // fc1_wT[j][c]
    int j = idx / CC, c = idx - j * CC;
    fc1_wT[idx] = f2bf(fc1_w[c * MLPH + j]);
    return;
  }
  idx -= 36864;
  if (idx < 36864) {                       // fc2_wT[c][j]
    int c = idx / MLPH, j = idx - c * MLPH;
    fc2_wT[idx] = f2bf(fc2_w[j * CC + c]);
  }
}

// ---------------- K0b: biasT[head][q][kv] = rpb[ridx(q,kv)*3+head] ----------------
__global__ __launch_bounds__(256) void bias_kernel(const float* __restrict__ rpb,
                                                   float* __restrict__ biasT) {
  int idx = blockIdx.x * 256 + threadIdx.x;
  if (idx >= NHEADS * NN * NN) return;
  int head = idx / (NN * NN);
  int r = idx - head * NN * NN;
  int q = r / NN, kv = r - q * NN;
  int itq = q / 49, rq = q - itq * 49, ihq = rq / 7, iwq = rq - ihq * 7;
  int itk = kv / 49, rk = kv - itk * 49, ihk = rk / 7, iwk = rk - ihk * 7;
  int ridx = (itq - itk + 1) * 169 + (ihq - ihk + 6) * 13 + (iwq - iwk + 6);
  biasT[idx] = rpb[ridx * NHEADS + head];
}

// ---------------- K0c: LN1 + shift-roll + window gather -> xnw[widx][112][96] bf16 ----------------
__global__ __launch_bounds__(256) void ln1_kernel(
    const float* __restrict__ x, const float* __restrict__ g1, const float* __restrict__ b1,
    u16* __restrict__ xnw)
{
  const int tid = threadIdx.x;
  const int row = blockIdx.x * 64 + (tid >> 2);   // 0 .. NWIN*112-1
  const int qd = tid & 3;                          // quarter: 24 channels
  const int widx = row / 112;
  const int n = row - widx * 112;
  u16* dst = xnw + (size_t)row * CC + qd * 24;
  if (n >= NN) {                                   // pad row -> zeros
    uint4 z = {0u, 0u, 0u, 0u};
    *(uint4*)(dst) = z; *(uint4*)(dst + 8) = z; *(uint4*)(dst + 16) = z;
    return;
  }
  int it = n / 49, r = n - it * 49, ih = r / 7, iw = r - ih * 7;
  int ww = widx & 15, hw = (widx >> 4) & 15, tw = widx >> 8;
  int t = tw * 2 + it + 1; if (t >= TT) t -= TT;
  int h = hw * 7 + ih + 3; if (h >= HH) h -= HH;
  int w = ww * 7 + iw + 3; if (w >= WD) w -= WD;
  const float* src = x + ((size_t)(t * HH + h) * WD + w) * CC + qd * 24;
  float v[24];
  #pragma unroll
  for (int i = 0; i < 24; i += 4) {
    float4 f = *(const float4*)(src + i);
    v[i] = f.x; v[i + 1] = f.y; v[i + 2] = f.z; v[i + 3] = f.w;
  }
  float sm = 0.f;
  #pragma unroll
  for (int i = 0; i < 24; ++i) sm += v[i];
  sm += __shfl_xor(sm, 1, 64);
  sm += __shfl_xor(sm, 2, 64);
  float mu = sm * (1.f / CC);
  float sq = 0.f;
  #pragma unroll
  for (int i = 0; i < 24; ++i) { float d = v[i] - mu; sq += d * d; }
  sq += __shfl_xor(sq, 1, 64);
  sq += __shfl_xor(sq, 2, 64);
  float inv = rsqrtf(sq * (1.f / CC) + 1e-5f);
  u16 o[24];
  #pragma unroll
  for (int i = 0; i < 24; ++i) {
    int c = qd * 24 + i;
    o[i] = f2bf((v[i] - mu) * inv * g1[c] + b1[c]);
  }
  *(uint4*)(dst)      = *(const uint4*)(o);
  *(uint4*)(dst + 8)  = *(const uint4*)(o + 8);
  *(uint4*)(dst + 16) = *(const uint4*)(o + 16);
}

// ---------------- K1: per-(window,head) QKV + attention (MFMA) ----------------
__global__ __launch_bounds__(256, 4) void attn_kernel(
    const u16* __restrict__ xnw, const u16* __restrict__ qkv_wT, const float* __restrict__ qkv_b,
    const float* __restrict__ biasT, u16* __restrict__ att)
{
  // union buffer: phases 1-2 -> sQ[112][40] + sK[112][40]; phases 3-4 -> sP[112][136]
  __shared__ __align__(16) u16 sUni[112 * SVP];   // 30464 B
  __shared__ __align__(16) u16 sVt[32 * SVP];     //  8704 B  [d][kv]
  __shared__ int sReg[112];

  u16* sQ = sUni;
  u16* sK = sUni + 112 * SQP;
  u16* sP = sUni;

  const int tid  = threadIdx.x;
  const int bid  = blockIdx.x;
  const int widx = bid / 3;
  const int head = bid - widx * 3;
  const int ww = widx & 15, hw = (widx >> 4) & 15, tw = widx >> 8;
  const bool bnd = (tw == 7) || (hw == 15) || (ww == 15);
  const int wid = tid >> 6;          // wave 0..3
  const int lane = tid & 63;
  const int g  = lane >> 4;          // lane group 0..3
  const int cl = lane & 15;          // col-in-tile

  // ---- phase 0: zero sVt (pad kv cols must be 0) + region ids
  for (int i = tid; i < 32 * SVP / 2; i += 256) ((u32*)sVt)[i] = 0;
  if (tid < 112) {
    int n = tid;
    int reg = 0;
    if (n < NN) {
      int it = n / 49, r = n - it * 49, ih = r / 7, iw = r - ih * 7;
      int ts = tw * 2 + it, hs = hw * 7 + ih, ws2 = ww * 7 + iw;
      int rt = ts < TT - 2 ? 0 : (ts < TT - 1 ? 1 : 2);
      int rh = hs < HH - 7 ? 0 : (hs < HH - 3 ? 1 : 2);
      int rw = ws2 < WD - 7 ? 0 : (ws2 < WD - 3 ? 1 : 2);
      reg = rt * 9 + rh * 3 + rw;
    }
    sReg[n] = reg;
  }
  __syncthreads();

  // ---- phase 1: QKV slice for this head (A-frags straight from global; D -> sQ/sK/sVt)
  {
    const float scale = 0.17677669529663687f;   // 32^-0.5
    #pragma unroll
    for (int mi = 0; mi < 2; ++mi) {
      const int mt = wid + mi * 4;
      if (mt < 7) {
        const u16* arow = xnw + ((size_t)widx * 112 + mt * 16 + cl) * CC + 8 * g;
        bf16x8 a0 = *(const bf16x8*)(arow);
        bf16x8 a1 = *(const bf16x8*)(arow + 32);
        bf16x8 a2 = *(const bf16x8*)(arow + 64);
        #pragma unroll
        for (int nt = 0; nt < 6; ++nt) {
          const int sec = nt >> 1;                      // 0=Q 1=K 2=V
          const int col = sec * 96 + head * 32 + (nt & 1) * 16 + cl;
          const u16* brow = qkv_wT + (size_t)col * CC + 8 * g;
          f32x4 acc = {0.f, 0.f, 0.f, 0.f};
          acc = MFMA16(a0, *(const bf16x8*)(brow), acc);
          acc = MFMA16(a1, *(const bf16x8*)(brow + 32), acc);
          acc = MFMA16(a2, *(const bf16x8*)(brow + 64), acc);
          const float bias = qkv_b[col];
          #pragma unroll
          for (int r = 0; r < 4; ++r) {
            const int row = mt * 16 + 4 * g + r;
            const float v = acc[r] + bias;
            if (sec == 0)      sQ[row * SQP + (nt & 1) * 16 + cl] = f2bf(v * scale);
            else if (sec == 1) sK[row * SQP + (nt & 1) * 16 + cl] = f2bf(v);
            else               sVt[((nt & 1) * 16 + cl) * SVP + row] = f2bf(v);
          }
        }
      }
    }
  }
  __syncthreads();

  // ---- phase 2: QK^T (MFMA, K=32) + bias/mask + in-register softmax
  float sv[2][7][4];
  #pragma unroll
  for (int mi = 0; mi < 2; ++mi) {
    const int mt = wid + mi * 4;
    if (mt >= 7) continue;
    bf16x8 a = *(const bf16x8*)&sQ[(mt * 16 + cl) * SQP + 8 * g];
    #pragma unroll
    for (int nt = 0; nt < 7; ++nt) {
      bf16x8 b = *(const bf16x8*)&sK[(nt * 16 + cl) * SQP + 8 * g];
      f32x4 acc = {0.f, 0.f, 0.f, 0.f};
      acc = MFMA16(a, b, acc);
      #pragma unroll
      for (int r = 0; r < 4; ++r) sv[mi][nt][r] = acc[r];
    }
    const int q0 = mt * 16 + 4 * g;
    #pragma unroll
    for (int nt = 0; nt < 7; ++nt) {
      const int kv = nt * 16 + cl;
      #pragma unroll
      for (int r = 0; r < 4; ++r) {
        const int q = q0 + r;
        float v = sv[mi][nt][r];
        if (kv < NN) {
          if (q < NN) {
            v += biasT[((head * NN + q)) * NN + kv];
            if (bnd && sReg[q] != sReg[kv]) v -= 100.f;
          }
        } else {
          v = -1e30f;
        }
        sv[mi][nt][r] = v;
      }
    }
    #pragma unroll
    for (int r = 0; r < 4; ++r) {
      float mx = sv[mi][0][r];
      #pragma unroll
      for (int nt = 1; nt < 7; ++nt) mx = fmaxf(mx, sv[mi][nt][r]);
      #pragma unroll
      for (int d = 1; d < 16; d <<= 1) mx = fmaxf(mx, __shfl_xor(mx, d, 64));
      float sm = 0.f;
      #pragma unroll
      for (int nt = 0; nt < 7; ++nt) { float p = __expf(sv[mi][nt][r] - mx); sv[mi][nt][r] = p; sm += p; }
      #pragma unroll
      for (int d = 1; d < 16; d <<= 1) sm += __shfl_xor(sm, d, 64);
      const float inv = 1.f / sm;
      #pragma unroll
      for (int nt = 0; nt < 7; ++nt) sv[mi][nt][r] *= inv;
    }
  }
  __syncthreads();   // all Q/K reads complete before P overwrites the union buffer

  // ---- phase 3: write P (bf16) + zero pad cols 112..127
  #pragma unroll
  for (int mi = 0; mi < 2; ++mi) {
    const int mt = wid + mi * 4;
    if (mt >= 7) continue;
    #pragma unroll
    for (int r = 0; r < 4; ++r) {
      const int q = mt * 16 + 4 * g + r;
      u16* prow = &sP[q * SVP];
      #pragma unroll
      for (int nt = 0; nt < 7; ++nt) prow[nt * 16 + cl] = f2bf(sv[mi][nt][r]);
      prow[112 + cl] = 0;
    }
  }
  __syncthreads();

  // ---- phase 4: PV (MFMA, K=128) + store
  for (int t = wid; t < 14; t += 4) {
    const int mt = t >> 1, ntd = t & 1;
    f32x4 acc = {0.f, 0.f, 0.f, 0.f};
    #pragma unroll
    for (int ks = 0; ks < 4; ++ks) {
      bf16x8 a = *(const bf16x8*)&sP[(mt * 16 + cl) * SVP + ks * 32 + 8 * g];
      bf16x8 b = *(const bf16x8*)&sVt[(ntd * 16 + cl) * SVP + ks * 32 + 8 * g];
      acc = MFMA16(a, b, acc);
    }
    #pragma unroll
    for (int r = 0; r < 4; ++r) {
      const int q = mt * 16 + 4 * g + r;
      if (q < NN)
        att[((size_t)widx * NN + q) * CC + head * 32 + ntd * 16 + cl] = f2bf(acc[r]);
    }
  }
}

// ---------------- K2: proj (MFMA) + reverse window + un-roll + residual ----------------
__global__ __launch_bounds__(256) void proj_kernel(
    const u16* __restrict__ att, const u16* __restrict__ proj_wT, const float* __restrict__ proj_b,
    const float* __restrict__ x, float* __restrict__ x1)
{
  __shared__ __align__(16) u16 sA[64 * SXP];   // 13312 B
  const int tid = threadIdx.x;
  const int base = blockIdx.x * 64;            // window-token index
  const int wid = tid >> 6, lane = tid & 63, g = lane >> 4, cl = lane & 15;

  for (int e = tid; e < 64 * (CC / 8); e += 256) {
    int tok = e / 12, kb = e - tok * 12;
    *(uint4*)&sA[tok * SXP + kb * 8] =
        ((const uint4*)att)[((size_t)(base + tok) * CC + kb * 8) >> 3];
  }
  __syncthreads();

  size_t rowOff[4];
  #pragma unroll
  for (int r = 0; r < 4; ++r) {
    int tok = base + wid * 16 + 4 * g + r;
    int widx = tok / NN, n = tok - widx * NN;
    int ww = widx & 15, hw = (widx >> 4) & 15, tw = widx >> 8;
    int it = n / 49, rr = n - it * 49, ih = rr / 7, iw = rr - ih * 7;
    int t = tw * 2 + it + 1; if (t >= TT) t -= TT;
    int h = hw * 7 + ih + 3; if (h >= HH) h -= HH;
    int w = ww * 7 + iw + 3; if (w >= WD) w -= WD;
    rowOff[r] = ((size_t)(t * HH + h) * WD + w) * CC;
  }

  const u16* aRow = &sA[(wid * 16 + cl) * SXP + 8 * g];
  bf16x8 a0 = *(const bf16x8*)(aRow);
  bf16x8 a1 = *(const bf16x8*)(aRow + 32);
  bf16x8 a2 = *(const bf16x8*)(aRow + 64);
  for (int nt = 0; nt < 6; ++nt) {
    const u16* bRow = proj_wT + (nt * 16 + cl) * CC + 8 * g;
    f32x4 acc = {0.f, 0.f, 0.f, 0.f};
    acc = MFMA16(a0, *(const bf16x8*)(bRow), acc);
    acc = MFMA16(a1, *(const bf16x8*)(bRow + 32), acc);
    acc = MFMA16(a2, *(const bf16x8*)(bRow + 64), acc);
    float bc = proj_b[nt * 16 + cl];
    #pragma unroll
    for (int r = 0; r < 4; ++r) {
      size_t off = rowOff[r] + nt * 16 + cl;
      x1[off] = x[off] + acc[r] + bc;
    }
  }
}

// ---------------- K3: LN2 + FC1 + exact GELU + FC2 + residual (MFMA) ----------------
__global__ __launch_bounds__(256) void mlp_kernel(
    const float* __restrict__ x1, const float* __restrict__ g2, const float* __restrict__ b2,
    const u16* __restrict__ fc1_wT, const float* __restrict__ fc1_b,
    const u16* __restrict__ fc2_wT, const float* __restrict__ fc2_b,
    float* __restrict__ out)
{
  __shared__ __align__(16) u16 sXn[64 * SXP];   // 13312 B
  __shared__ __align__(16) u16 sH [64 * SHP];   // 50176 B
  const int tid = threadIdx.x;
  const size_t base = (size_t)blockIdx.x * 64;
  const int wid = tid >> 6, lane = tid & 63, g = lane >> 4, cl = lane & 15;

  // ---- LN2: token = tid>>2, quarter = tid&3 (24 channels each); 4-lane shfl reduce
  {
    const int tok = tid >> 2, qd = tid & 3;
    const float* row = x1 + (base + tok) * CC + qd * 24;
    float v[24];
    #pragma unroll
    for (int i = 0; i < 24; i += 4) {
      float4 f = *(const float4*)(row + i);
      v[i] = f.x; v[i + 1] = f.y; v[i + 2] = f.z; v[i + 3] = f.w;
    }
    float sm = 0.f;
    #pragma unroll
    for (int i = 0; i < 24; ++i) sm += v[i];
    sm += __shfl_xor(sm, 1, 64);
    sm += __shfl_xor(sm, 2, 64);
    float mu = sm * (1.f / CC);
    float sq = 0.f;
    #pragma unroll
    for (int i = 0; i < 24; ++i) { float d = v[i] - mu; sq += d * d; }
    sq += __shfl_xor(sq, 1, 64);
    sq += __shfl_xor(sq, 2, 64);
    float inv = rsqrtf(sq * (1.f / CC) + 1e-5f);
    #pragma unroll
    for (int i = 0; i < 24; ++i) {
      int c = qd * 24 + i;
      sXn[tok * SXP + c] = f2bf((v[i] - mu) * inv * g2[c] + b2[c]);
    }
  }
  __syncthreads();

  // ---- GEMM1 [64x96]@[96x384] + GELU -> sH (bf16)
  {
    const u16* aRow = &sXn[(wid * 16 + cl) * SXP + 8 * g];
    bf16x8 a0 = *(const bf16x8*)(aRow);
    bf16x8 a1 = *(const bf16x8*)(aRow + 32);
    bf16x8 a2 = *(const bf16x8*)(aRow + 64);
    for (int nt = 0; nt < 24; ++nt) {
      const u16* bRow = fc1_wT + (nt * 16 + cl) * CC + 8 * g;
      f32x4 acc = {0.f, 0.f, 0.f, 0.f};
      acc = MFMA16(a0, *(const bf16x8*)(bRow), acc);
      acc = MFMA16(a1, *(const bf16x8*)(bRow + 32), acc);
      acc = MFMA16(a2, *(const bf16x8*)(bRow + 64), acc);
      float bj = fc1_b[nt * 16 + cl];
      #pragma unroll
      for (int r = 0; r < 4; ++r) {
        float v = acc[r] + bj;
        v = 0.5f * v * (1.f + erff(v * 0.70710678118654752f));
        sH[(wid * 16 + 4 * g + r) * SHP + nt * 16 + cl] = f2bf(v);
      }
    }
  }
  __syncthreads();

  // ---- GEMM2 [64x384]@[384x96] + residual -> out
  {
    const u16* aBase = &sH[(wid * 16 + cl) * SHP + 8 * g];
    bf16x8 a[12];
    #pragma unroll
    for (int ks = 0; ks < 12; ++ks) a[ks] = *(const bf16x8*)(aBase + 32 * ks);
    for (int nt = 0; nt < 6; ++nt) {
      const u16* bBase = fc2_wT + (nt * 16 + cl) * MLPH + 8 * g;
      f32x4 acc = {0.f, 0.f, 0.f, 0.f};
      #pragma unroll
      for (int ks = 0; ks < 12; ++ks)
        acc = MFMA16(a[ks], *(const bf16x8*)(bBase + 32 * ks), acc);
      float bc = fc2_b[nt * 16 + cl];
      #pragma unroll
      for (int r = 0; r < 4; ++r) {
        size_t off = (base + wid * 16 + 4 * g + r) * CC + nt * 16 + cl;
        out[off] = x1[off] + acc[r] + bc;
      }
    }
  }
}

extern "C" void kernel_launch(void* const* d_in, const int* in_sizes, int n_in,
                              void* d_out, int out_size, void* d_ws, size_t ws_size,
                              hipStream_t stream) {
  const float* x      = (const float*)d_in[0];
  const float* g1     = (const float*)d_in[1];
  const float* b1     = (const float*)d_in[2];
  const float* qkv_w  = (const float*)d_in[3];
  const float* qkv_b  = (const float*)d_in[4];
  const float* rpb    = (const float*)d_in[5];
  const float* proj_w = (const float*)d_in[6];
  const float* proj_b = (const float*)d_in[7];
  const float* g2     = (const float*)d_in[8];
  const float* b2     = (const float*)d_in[9];
  const float* fc1_w  = (const float*)d_in[10];
  const float* fc1_b  = (const float*)d_in[11];
  const float* fc2_w  = (const float*)d_in[12];
  const float* fc2_b  = (const float*)d_in[13];

  char* ws = (char*)d_ws;
  u16*   att    = (u16*)ws;                                   // 38.5 MB
  float* x1     = (float*)(ws + (size_t)NTOK * CC * 2);       // 77 MB (xnw aliases this region)
  u16*   xnw    = (u16*)x1;                                   // NWIN*112*96 bf16 = 44 MB (dead before proj writes x1)
  char*  wtail  = ws + (size_t)NTOK * CC * 6;
  float* biasT  = (float*)wtail;                              // 115248 B
  u16*   qkv_wT = (u16*)(wtail + 115248);                     // 55296 B
  u16*   proj_wT= (u16*)(wtail + 115248 + 55296);             // 18432 B
  u16*   fc1_wT = (u16*)(wtail + 115248 + 55296 + 18432);     // 73728 B
  u16*   fc2_wT = (u16*)(wtail + 115248 + 55296 + 18432 + 73728); // 73728 B

  wprep_kernel<<<(27648 + 9216 + 36864 + 36864 + 255) / 256, 256, 0, stream>>>(
      qkv_w, proj_w, fc1_w, fc2_w, qkv_wT, proj_wT, fc1_wT, fc2_wT);
  bias_kernel<<<(NHEADS * NN * NN + 255) / 256, 256, 0, stream>>>(rpb, biasT);
  ln1_kernel<<<NWIN * 112 / 64, 256, 0, stream>>>(x, g1, b1, xnw);
  attn_kernel<<<NWIN * NHEADS, 256, 0, stream>>>(xnw, qkv_wT, qkv_b, biasT, att);
  proj_kernel<<<NTOK / 64, 256, 0, stream>>>(att, proj_wT, proj_b, x, x1);
  mlp_kernel<<<NTOK / 64, 256, 0, stream>>>(x1, g2, b2, fc1_wT, fc1_b, fc2_wT, fc2_b, (float*)d_out);
}

// Round 6
// 387.218 us; speedup vs baseline: 8.9300x; 1.2238x over previous
//
#include <hip/hip_runtime.h>
#include <math.h>

#define TT 16
#define HH 112
#define WD 112
#define CC 96
#define NHEADS 3
#define HD 32
#define NN 98          // window tokens 2*7*7
#define NWIN 2048      // 8*16*16
#define NTOK 200704    // T*H*W == NWIN*NN
#define MLPH 384
#define SXP 104        // row stride (bf16) for mlp/proj LDS tiles
#define SQP 40         // row stride (bf16) for per-head sQ/sK (32 cols + 8 pad)
#define SVP 136        // row stride (bf16) for sVt/sP (128 cols + 8 pad)
#define SHP 392        // row stride (bf16) for sH
#define MTOK 32        // tokens per mlp block

typedef unsigned int  u32;
typedef unsigned short u16;
typedef float f32x4 __attribute__((ext_vector_type(4)));
typedef short bf16x8 __attribute__((ext_vector_type(8)));

__device__ inline u16 f2bf(float f) {
  u32 u = __float_as_uint(f);
  u += 0x7fffu + ((u >> 16) & 1u);
  return (u16)(u >> 16);
}
__device__ inline float bflo(u32 u) { return __uint_as_float(u << 16); }
__device__ inline float bfhi(u32 u) { return __uint_as_float(u & 0xffff0000u); }

#define MFMA16(a, b, c) __builtin_amdgcn_mfma_f32_16x16x32_bf16((a), (b), (c), 0, 0, 0)

// ---------------- K0a: transpose all weights to bf16 col-major ----------------
__global__ __launch_bounds__(256) void wprep_kernel(
    const float* __restrict__ qkv_w, const float* __restrict__ proj_w,
    const float* __restrict__ fc1_w, const float* __restrict__ fc2_w,
    u16* __restrict__ qkv_wT, u16* __restrict__ proj_wT,
    u16* __restrict__ fc1_wT, u16* __restrict__ fc2_wT) {
  int idx = blockIdx.x * 256 + threadIdx.x;
  if (idx < 27648) {                       // qkv_wT[col][c]
    int col = idx / CC, c = idx - col * CC;
    qkv_wT[idx] = f2bf(qkv_w[c * (3 * CC) + col]);
    return;
  }
  idx -= 27648;
  if (idx < 9216) {                        // proj_wT[col][c]
    int col = idx / CC, c = idx - col * CC;
    proj_wT[idx] = f2bf(proj_w[c * CC + col]);
    return;
  }
  idx -= 9216;
  if (idx < 36864) {                       // fc1_wT[j][c]
    int j = idx / CC, c = idx - j * CC;
    fc1_wT[idx] = f2bf(fc1_w[c * MLPH + j]);
    return;
  }
  idx -= 36864;
  if (idx < 36864) {                       // fc2_wT[c][j]
    int c = idx / MLPH, j = idx - c * MLPH;
    fc2_wT[idx] = f2bf(fc2_w[j * CC + c]);
  }
}

// ---------------- K0b: biasT[head][q][kv] = rpb[ridx(q,kv)*3+head] ----------------
__global__ __launch_bounds__(256) void bias_kernel(const float* __restrict__ rpb,
                                                   float* __restrict__ biasT) {
  int idx = blockIdx.x * 256 + threadIdx.x;
  if (idx >= NHEADS * NN * NN) return;
  int head = idx / (NN * NN);
  int r = idx - head * NN * NN;
  int q = r / NN, kv = r - q * NN;
  int itq = q / 49, rq = q - itq * 49, ihq = rq / 7, iwq = rq - ihq * 7;
  int itk = kv / 49, rk = kv - itk * 49, ihk = rk / 7, iwk = rk - ihk * 7;
  int ridx = (itq - itk + 1) * 169 + (ihq - ihk + 6) * 13 + (iwq - iwk + 6);
  biasT[idx] = rpb[ridx * NHEADS + head];
}

// ---------------- K0c: LN1 + shift-roll + window gather -> xnw[widx][112][96] bf16 ----------------
__global__ __launch_bounds__(256) void ln1_kernel(
    const float* __restrict__ x, const float* __restrict__ g1, const float* __restrict__ b1,
    u16* __restrict__ xnw)
{
  const int tid = threadIdx.x;
  const int row = blockIdx.x * 64 + (tid >> 2);   // 0 .. NWIN*112-1
  const int qd = tid & 3;                          // quarter: 24 channels
  const int widx = row / 112;
  const int n = row - widx * 112;
  u16* dst = xnw + (size_t)row * CC + qd * 24;
  if (n >= NN) {                                   // pad row -> zeros
    uint4 z = {0u, 0u, 0u, 0u};
    *(uint4*)(dst) = z; *(uint4*)(dst + 8) = z; *(uint4*)(dst + 16) = z;
    return;
  }
  int it = n / 49, r = n - it * 49, ih = r / 7, iw = r - ih * 7;
  int ww = widx & 15, hw = (widx >> 4) & 15, tw = widx >> 8;
  int t = tw * 2 + it + 1; if (t >= TT) t -= TT;
  int h = hw * 7 + ih + 3; if (h >= HH) h -= HH;
  int w = ww * 7 + iw + 3; if (w >= WD) w -= WD;
  const float* src = x + ((size_t)(t * HH + h) * WD + w) * CC + qd * 24;
  float v[24];
  #pragma unroll
  for (int i = 0; i < 24; i += 4) {
    float4 f = *(const float4*)(src + i);
    v[i] = f.x; v[i + 1] = f.y; v[i + 2] = f.z; v[i + 3] = f.w;
  }
  float sm = 0.f;
  #pragma unroll
  for (int i = 0; i < 24; ++i) sm += v[i];
  sm += __shfl_xor(sm, 1, 64);
  sm += __shfl_xor(sm, 2, 64);
  float mu = sm * (1.f / CC);
  float sq = 0.f;
  #pragma unroll
  for (int i = 0; i < 24; ++i) { float d = v[i] - mu; sq += d * d; }
  sq += __shfl_xor(sq, 1, 64);
  sq += __shfl_xor(sq, 2, 64);
  float inv = rsqrtf(sq * (1.f / CC) + 1e-5f);
  u16 o[24];
  #pragma unroll
  for (int i = 0; i < 24; ++i) {
    int c = qd * 24 + i;
    o[i] = f2bf((v[i] - mu) * inv * g1[c] + b1[c]);
  }
  *(uint4*)(dst)      = *(const uint4*)(o);
  *(uint4*)(dst + 8)  = *(const uint4*)(o + 8);
  *(uint4*)(dst + 16) = *(const uint4*)(o + 16);
}

// ---------------- K1: per-(window,head) QKV + attention (MFMA) ----------------
__global__ __launch_bounds__(256, 4) void attn_kernel(
    const u16* __restrict__ xnw, const u16* __restrict__ qkv_wT, const float* __restrict__ qkv_b,
    const float* __restrict__ biasT, u16* __restrict__ att)
{
  // union buffer: phases 1-2 -> sQ[112][40] + sK[112][40]; phases 3-4 -> sP[112][136]
  __shared__ __align__(16) u16 sUni[112 * SVP];   // 30464 B
  __shared__ __align__(16) u16 sVt[32 * SVP];     //  8704 B  [d][kv]
  __shared__ int sReg[112];

  u16* sQ = sUni;
  u16* sK = sUni + 112 * SQP;
  u16* sP = sUni;

  const int tid  = threadIdx.x;
  const int bid  = blockIdx.x;
  const int widx = bid / 3;
  const int head = bid - widx * 3;
  const int ww = widx & 15, hw = (widx >> 4) & 15, tw = widx >> 8;
  const bool bnd = (tw == 7) || (hw == 15) || (ww == 15);
  const int wid = tid >> 6;          // wave 0..3
  const int lane = tid & 63;
  const int g  = lane >> 4;          // lane group 0..3
  const int cl = lane & 15;          // col-in-tile

  // ---- phase 0: zero sVt (pad kv cols must be 0) + region ids
  for (int i = tid; i < 32 * SVP / 2; i += 256) ((u32*)sVt)[i] = 0;
  if (tid < 112) {
    int n = tid;
    int reg = 0;
    if (n < NN) {
      int it = n / 49, r = n - it * 49, ih = r / 7, iw = r - ih * 7;
      int ts = tw * 2 + it, hs = hw * 7 + ih, ws2 = ww * 7 + iw;
      int rt = ts < TT - 2 ? 0 : (ts < TT - 1 ? 1 : 2);
      int rh = hs < HH - 7 ? 0 : (hs < HH - 3 ? 1 : 2);
      int rw = ws2 < WD - 7 ? 0 : (ws2 < WD - 3 ? 1 : 2);
      reg = rt * 9 + rh * 3 + rw;
    }
    sReg[n] = reg;
  }
  __syncthreads();

  // ---- phase 1: QKV slice for this head (A-frags straight from global; D -> sQ/sK/sVt)
  {
    const float scale = 0.17677669529663687f;   // 32^-0.5
    #pragma unroll
    for (int mi = 0; mi < 2; ++mi) {
      const int mt = wid + mi * 4;
      if (mt < 7) {
        const u16* arow = xnw + ((size_t)widx * 112 + mt * 16 + cl) * CC + 8 * g;
        bf16x8 a0 = *(const bf16x8*)(arow);
        bf16x8 a1 = *(const bf16x8*)(arow + 32);
        bf16x8 a2 = *(const bf16x8*)(arow + 64);
        #pragma unroll
        for (int nt = 0; nt < 6; ++nt) {
          const int sec = nt >> 1;                      // 0=Q 1=K 2=V
          const int col = sec * 96 + head * 32 + (nt & 1) * 16 + cl;
          const u16* brow = qkv_wT + (size_t)col * CC + 8 * g;
          f32x4 acc = {0.f, 0.f, 0.f, 0.f};
          acc = MFMA16(a0, *(const bf16x8*)(brow), acc);
          acc = MFMA16(a1, *(const bf16x8*)(brow + 32), acc);
          acc = MFMA16(a2, *(const bf16x8*)(brow + 64), acc);
          const float bias = qkv_b[col];
          #pragma unroll
          for (int r = 0; r < 4; ++r) {
            const int row = mt * 16 + 4 * g + r;
            const float v = acc[r] + bias;
            if (sec == 0)      sQ[row * SQP + (nt & 1) * 16 + cl] = f2bf(v * scale);
            else if (sec == 1) sK[row * SQP + (nt & 1) * 16 + cl] = f2bf(v);
            else               sVt[((nt & 1) * 16 + cl) * SVP + row] = f2bf(v);
          }
        }
      }
    }
  }
  __syncthreads();

  // ---- phase 2: QK^T (MFMA, K=32) + bias/mask + in-register softmax
  float sv[2][7][4];
  #pragma unroll
  for (int mi = 0; mi < 2; ++mi) {
    const int mt = wid + mi * 4;
    if (mt >= 7) continue;
    bf16x8 a = *(const bf16x8*)&sQ[(mt * 16 + cl) * SQP + 8 * g];
    #pragma unroll
    for (int nt = 0; nt < 7; ++nt) {
      bf16x8 b = *(const bf16x8*)&sK[(nt * 16 + cl) * SQP + 8 * g];
      f32x4 acc = {0.f, 0.f, 0.f, 0.f};
      acc = MFMA16(a, b, acc);
      #pragma unroll
      for (int r = 0; r < 4; ++r) sv[mi][nt][r] = acc[r];
    }
    const int q0 = mt * 16 + 4 * g;
    #pragma unroll
    for (int nt = 0; nt < 7; ++nt) {
      const int kv = nt * 16 + cl;
      #pragma unroll
      for (int r = 0; r < 4; ++r) {
        const int q = q0 + r;
        float v = sv[mi][nt][r];
        if (kv < NN) {
          if (q < NN) {
            v += biasT[((head * NN + q)) * NN + kv];
            if (bnd && sReg[q] != sReg[kv]) v -= 100.f;
          }
        } else {
          v = -1e30f;
        }
        sv[mi][nt][r] = v;
      }
    }
    #pragma unroll
    for (int r = 0; r < 4; ++r) {
      float mx = sv[mi][0][r];
      #pragma unroll
      for (int nt = 1; nt < 7; ++nt) mx = fmaxf(mx, sv[mi][nt][r]);
      #pragma unroll
      for (int d = 1; d < 16; d <<= 1) mx = fmaxf(mx, __shfl_xor(mx, d, 64));
      float sm = 0.f;
      #pragma unroll
      for (int nt = 0; nt < 7; ++nt) { float p = __expf(sv[mi][nt][r] - mx); sv[mi][nt][r] = p; sm += p; }
      #pragma unroll
      for (int d = 1; d < 16; d <<= 1) sm += __shfl_xor(sm, d, 64);
      const float inv = 1.f / sm;
      #pragma unroll
      for (int nt = 0; nt < 7; ++nt) sv[mi][nt][r] *= inv;
    }
  }
  __syncthreads();   // all Q/K reads complete before P overwrites the union buffer

  // ---- phase 3: write P (bf16) + zero pad cols 112..127
  #pragma unroll
  for (int mi = 0; mi < 2; ++mi) {
    const int mt = wid + mi * 4;
    if (mt >= 7) continue;
    #pragma unroll
    for (int r = 0; r < 4; ++r) {
      const int q = mt * 16 + 4 * g + r;
      u16* prow = &sP[q * SVP];
      #pragma unroll
      for (int nt = 0; nt < 7; ++nt) prow[nt * 16 + cl] = f2bf(sv[mi][nt][r]);
      prow[112 + cl] = 0;
    }
  }
  __syncthreads();

  // ---- phase 4: PV (MFMA, K=128) + store
  for (int t = wid; t < 14; t += 4) {
    const int mt = t >> 1, ntd = t & 1;
    f32x4 acc = {0.f, 0.f, 0.f, 0.f};
    #pragma unroll
    for (int ks = 0; ks < 4; ++ks) {
      bf16x8 a = *(const bf16x8*)&sP[(mt * 16 + cl) * SVP + ks * 32 + 8 * g];
      bf16x8 b = *(const bf16x8*)&sVt[(ntd * 16 + cl) * SVP + ks * 32 + 8 * g];
      acc = MFMA16(a, b, acc);
    }
    #pragma unroll
    for (int r = 0; r < 4; ++r) {
      const int q = mt * 16 + 4 * g + r;
      if (q < NN)
        att[((size_t)widx * NN + q) * CC + head * 32 + ntd * 16 + cl] = f2bf(acc[r]);
    }
  }
}

// ---------------- K2: proj (MFMA) + reverse window + un-roll + residual ----------------
__global__ __launch_bounds__(256) void proj_kernel(
    const u16* __restrict__ att, const u16* __restrict__ proj_wT, const float* __restrict__ proj_b,
    const float* __restrict__ x, float* __restrict__ x1)
{
  __shared__ __align__(16) u16 sA[64 * SXP];   // 13312 B
  const int tid = threadIdx.x;
  const int base = blockIdx.x * 64;            // window-token index
  const int wid = tid >> 6, lane = tid & 63, g = lane >> 4, cl = lane & 15;

  for (int e = tid; e < 64 * (CC / 8); e += 256) {
    int tok = e / 12, kb = e - tok * 12;
    *(uint4*)&sA[tok * SXP + kb * 8] =
        ((const uint4*)att)[((size_t)(base + tok) * CC + kb * 8) >> 3];
  }
  __syncthreads();

  size_t rowOff[4];
  #pragma unroll
  for (int r = 0; r < 4; ++r) {
    int tok = base + wid * 16 + 4 * g + r;
    int widx = tok / NN, n = tok - widx * NN;
    int ww = widx & 15, hw = (widx >> 4) & 15, tw = widx >> 8;
    int it = n / 49, rr = n - it * 49, ih = rr / 7, iw = rr - ih * 7;
    int t = tw * 2 + it + 1; if (t >= TT) t -= TT;
    int h = hw * 7 + ih + 3; if (h >= HH) h -= HH;
    int w = ww * 7 + iw + 3; if (w >= WD) w -= WD;
    rowOff[r] = ((size_t)(t * HH + h) * WD + w) * CC;
  }

  const u16* aRow = &sA[(wid * 16 + cl) * SXP + 8 * g];
  bf16x8 a0 = *(const bf16x8*)(aRow);
  bf16x8 a1 = *(const bf16x8*)(aRow + 32);
  bf16x8 a2 = *(const bf16x8*)(aRow + 64);
  for (int nt = 0; nt < 6; ++nt) {
    const u16* bRow = proj_wT + (nt * 16 + cl) * CC + 8 * g;
    f32x4 acc = {0.f, 0.f, 0.f, 0.f};
    acc = MFMA16(a0, *(const bf16x8*)(bRow), acc);
    acc = MFMA16(a1, *(const bf16x8*)(bRow + 32), acc);
    acc = MFMA16(a2, *(const bf16x8*)(bRow + 64), acc);
    float bc = proj_b[nt * 16 + cl];
    #pragma unroll
    for (int r = 0; r < 4; ++r) {
      size_t off = rowOff[r] + nt * 16 + cl;
      x1[off] = x[off] + acc[r] + bc;
    }
  }
}

// ---------------- K3: LN2 + FC1 + tanh-GELU + FC2 + residual (MFMA, 32 tok/block) ----------------
__global__ __launch_bounds__(256, 4) void mlp_kernel(
    const float* __restrict__ x1, const float* __restrict__ g2, const float* __restrict__ b2,
    const u16* __restrict__ fc1_wT, const float* __restrict__ fc1_b,
    const u16* __restrict__ fc2_wT, const float* __restrict__ fc2_b,
    float* __restrict__ out)
{
  __shared__ __align__(16) u16 sXn[MTOK * SXP];   //  6656 B
  __shared__ __align__(16) u16 sH [MTOK * SHP];   // 25088 B
  const int tid = threadIdx.x;
  const size_t base = (size_t)blockIdx.x * MTOK;
  const int wid = tid >> 6, lane = tid & 63, g = lane >> 4, cl = lane & 15;
  const int mt  = wid & 1;          // m-tile (16 tokens)
  const int hnt = wid >> 1;         // nt-range half

  // ---- LN2: token = tid>>3 (32), sub = tid&7 (12 channels each); 8-lane shfl reduce
  {
    const int tok = tid >> 3, sub = tid & 7;
    const float* row = x1 + (base + tok) * CC + sub * 12;
    float v[12];
    #pragma unroll
    for (int i = 0; i < 12; i += 4) {
      float4 f = *(const float4*)(row + i);
      v[i] = f.x; v[i + 1] = f.y; v[i + 2] = f.z; v[i + 3] = f.w;
    }
    float sm = 0.f;
    #pragma unroll
    for (int i = 0; i < 12; ++i) sm += v[i];
    sm += __shfl_xor(sm, 1, 64);
    sm += __shfl_xor(sm, 2, 64);
    sm += __shfl_xor(sm, 4, 64);
    float mu = sm * (1.f / CC);
    float sq = 0.f;
    #pragma unroll
    for (int i = 0; i < 12; ++i) { float d = v[i] - mu; sq += d * d; }
    sq += __shfl_xor(sq, 1, 64);
    sq += __shfl_xor(sq, 2, 64);
    sq += __shfl_xor(sq, 4, 64);
    float inv = rsqrtf(sq * (1.f / CC) + 1e-5f);
    #pragma unroll
    for (int i = 0; i < 12; ++i) {
      int c = sub * 12 + i;
      sXn[tok * SXP + c] = f2bf((v[i] - mu) * inv * g2[c] + b2[c]);
    }
  }
  __syncthreads();

  // ---- GEMM1 [32x96]@[96x384] + GELU -> sH (bf16); wave does m-tile mt, nts [hnt*12, +12)
  {
    const u16* aRow = &sXn[(mt * 16 + cl) * SXP + 8 * g];
    bf16x8 a0 = *(const bf16x8*)(aRow);
    bf16x8 a1 = *(const bf16x8*)(aRow + 32);
    bf16x8 a2 = *(const bf16x8*)(aRow + 64);
    const int nt0 = hnt * 12;
    const u16* bPtr = fc1_wT + ((size_t)(nt0 * 16 + cl)) * CC + 8 * g;
    bf16x8 b0 = *(const bf16x8*)(bPtr);
    bf16x8 b1 = *(const bf16x8*)(bPtr + 32);
    bf16x8 b2 = *(const bf16x8*)(bPtr + 64);
    for (int j = 0; j < 12; ++j) {
      bf16x8 c0 = b0, c1 = b1, c2 = b2;
      if (j < 11) {                       // prefetch next nt
        bPtr += 16 * CC;
        b0 = *(const bf16x8*)(bPtr);
        b1 = *(const bf16x8*)(bPtr + 32);
        b2 = *(const bf16x8*)(bPtr + 64);
      }
      f32x4 acc = {0.f, 0.f, 0.f, 0.f};
      acc = MFMA16(a0, c0, acc);
      acc = MFMA16(a1, c1, acc);
      acc = MFMA16(a2, c2, acc);
      const int nt = nt0 + j;
      float bj = fc1_b[nt * 16 + cl];
      #pragma unroll
      for (int r = 0; r < 4; ++r) {
        float v = acc[r] + bj;
        // tanh-form GELU: 0.5v(1+tanh(0.79788456(v+0.044715v^3)))
        float y = 0.79788456080286536f * (v + 0.044715f * v * v * v);
        float t = 1.f - 2.f / (__expf(2.f * y) + 1.f);
        sH[(mt * 16 + 4 * g + r) * SHP + nt * 16 + cl] = f2bf(0.5f * v * (1.f + t));
      }
    }
  }
  __syncthreads();

  // ---- GEMM2 [32x384]@[384x96] + residual; wave does m-tile mt, nts [hnt*3, +3)
  {
    const u16* aBase = &sH[(mt * 16 + cl) * SHP + 8 * g];
    bf16x8 a[12];
    #pragma unroll
    for (int ks = 0; ks < 12; ++ks) a[ks] = *(const bf16x8*)(aBase + 32 * ks);
    const int nt0 = hnt * 3;
    for (int j = 0; j < 3; ++j) {
      const int nt = nt0 + j;
      const u16* bBase = fc2_wT + ((size_t)(nt * 16 + cl)) * MLPH + 8 * g;
      f32x4 accA = {0.f, 0.f, 0.f, 0.f};
      f32x4 accB = {0.f, 0.f, 0.f, 0.f};
      #pragma unroll
      for (int ks = 0; ks < 6; ++ks) {
        accA = MFMA16(a[ks], *(const bf16x8*)(bBase + 32 * ks), accA);
        accB = MFMA16(a[ks + 6], *(const bf16x8*)(bBase + 32 * (ks + 6)), accB);
      }
      float bc = fc2_b[nt * 16 + cl];
      #pragma unroll
      for (int r = 0; r < 4; ++r) {
        size_t off = (base + mt * 16 + 4 * g + r) * CC + nt * 16 + cl;
        out[off] = x1[off] + accA[r] + accB[r] + bc;
      }
    }
  }
}

extern "C" void kernel_launch(void* const* d_in, const int* in_sizes, int n_in,
                              void* d_out, int out_size, void* d_ws, size_t ws_size,
                              hipStream_t stream) {
  const float* x      = (const float*)d_in[0];
  const float* g1     = (const float*)d_in[1];
  const float* b1     = (const float*)d_in[2];
  const float* qkv_w  = (const float*)d_in[3];
  const float* qkv_b  = (const float*)d_in[4];
  const float* rpb    = (const float*)d_in[5];
  const float* proj_w = (const float*)d_in[6];
  const float* proj_b = (const float*)d_in[7];
  const float* g2     = (const float*)d_in[8];
  const float* b2     = (const float*)d_in[9];
  const float* fc1_w  = (const float*)d_in[10];
  const float* fc1_b  = (const float*)d_in[11];
  const float* fc2_w  = (const float*)d_in[12];
  const float* fc2_b  = (const float*)d_in[13];

  char* ws = (char*)d_ws;
  u16*   att    = (u16*)ws;                                   // 38.5 MB
  float* x1     = (float*)(ws + (size_t)NTOK * CC * 2);       // 77 MB (xnw aliases this region)
  u16*   xnw    = (u16*)x1;                                   // NWIN*112*96 bf16 = 44 MB (dead before proj writes x1)
  char*  wtail  = ws + (size_t)NTOK * CC * 6;
  float* biasT  = (float*)wtail;                              // 115248 B
  u16*   qkv_wT = (u16*)(wtail + 115248);                     // 55296 B
  u16*   proj_wT= (u16*)(wtail + 115248 + 55296);             // 18432 B
  u16*   fc1_wT = (u16*)(wtail + 115248 + 55296 + 18432);     // 73728 B
  u16*   fc2_wT = (u16*)(wtail + 115248 + 55296 + 18432 + 73728); // 73728 B

  wprep_kernel<<<(27648 + 9216 + 36864 + 36864 + 255) / 256, 256, 0, stream>>>(
      qkv_w, proj_w, fc1_w, fc2_w, qkv_wT, proj_wT, fc1_wT, fc2_wT);
  bias_kernel<<<(NHEADS * NN * NN + 255) / 256, 256, 0, stream>>>(rpb, biasT);
  ln1_kernel<<<NWIN * 112 / 64, 256, 0, stream>>>(x, g1, b1, xnw);
  attn_kernel<<<NWIN * NHEADS, 256, 0, stream>>>(xnw, qkv_wT, qkv_b, biasT, att);
  proj_kernel<<<NTOK / 64, 256, 0, stream>>>(att, proj_wT, proj_b, x, x1);
  mlp_kernel<<<NTOK / MTOK, 256, 0, stream>>>(x1, g2, b2, fc1_wT, fc1_b, fc2_wT, fc2_b, (float*)d_out);
}

// Round 7
// 377.726 us; speedup vs baseline: 9.1544x; 1.0251x over previous
//
#include <hip/hip_runtime.h>
#include <math.h>

#define TT 16
#define HH 112
#define WD 112
#define CC 96
#define NHEADS 3
#define HD 32
#define NN 98          // window tokens 2*7*7
#define NWIN 2048      // 8*16*16
#define NTOK 200704    // T*H*W == NWIN*NN
#define MLPH 384
#define SXP 104        // row stride (bf16) LDS tiles (208B rows, 16B aligned)
#define SQP 40         // row stride (bf16) per-head sQ/sK
#define SVP 136        // row stride (bf16) sVt/sP
#define SH2P 200       // row stride (bf16) sH half (192 cols + 8 pad)
#define SX1P 100       // row stride (bf16) sX1

typedef unsigned int  u32;
typedef unsigned short u16;
typedef float f32x4 __attribute__((ext_vector_type(4)));
typedef short bf16x8 __attribute__((ext_vector_type(8)));

__device__ inline u16 f2bf(float f) {
  u32 u = __float_as_uint(f);
  u += 0x7fffu + ((u >> 16) & 1u);
  return (u16)(u >> 16);
}
__device__ inline float bflo(u32 u) { return __uint_as_float(u << 16); }
__device__ inline float bfhi(u32 u) { return __uint_as_float(u & 0xffff0000u); }

#define MFMA16(a, b, c) __builtin_amdgcn_mfma_f32_16x16x32_bf16((a), (b), (c), 0, 0, 0)

// ---------------- K0a: transpose all weights to bf16 col-major ----------------
__global__ __launch_bounds__(256) void wprep_kernel(
    const float* __restrict__ qkv_w, const float* __restrict__ proj_w,
    const float* __restrict__ fc1_w, const float* __restrict__ fc2_w,
    u16* __restrict__ qkv_wT, u16* __restrict__ proj_wT,
    u16* __restrict__ fc1_wT, u16* __restrict__ fc2_wT) {
  int idx = blockIdx.x * 256 + threadIdx.x;
  if (idx < 27648) {                       // qkv_wT[col][c]
    int col = idx / CC, c = idx - col * CC;
    qkv_wT[idx] = f2bf(qkv_w[c * (3 * CC) + col]);
    return;
  }
  idx -= 27648;
  if (idx < 9216) {                        // proj_wT[col][c]
    int col = idx / CC, c = idx - col * CC;
    proj_wT[idx] = f2bf(proj_w[c * CC + col]);
    return;
  }
  idx -= 9216;
  if (idx < 36864) {                       // fc1_wT[j][c]
    int j = idx / CC, c = idx - j * CC;
    fc1_wT[idx] = f2bf(fc1_w[c * MLPH + j]);
    return;
  }
  idx -= 36864;
  if (idx < 36864) {                       // fc2_wT[c][j]
    int c = idx / MLPH, j = idx - c * MLPH;
    fc2_wT[idx] = f2bf(fc2_w[j * CC + c]);
  }
}

// ---------------- K0b: biasT[head][q][kv] = rpb[ridx(q,kv)*3+head] ----------------
__global__ __launch_bounds__(256) void bias_kernel(const float* __restrict__ rpb,
                                                   float* __restrict__ biasT) {
  int idx = blockIdx.x * 256 + threadIdx.x;
  if (idx >= NHEADS * NN * NN) return;
  int head = idx / (NN * NN);
  int r = idx - head * NN * NN;
  int q = r / NN, kv = r - q * NN;
  int itq = q / 49, rq = q - itq * 49, ihq = rq / 7, iwq = rq - ihq * 7;
  int itk = kv / 49, rk = kv - itk * 49, ihk = rk / 7, iwk = rk - ihk * 7;
  int ridx = (itq - itk + 1) * 169 + (ihq - ihk + 6) * 13 + (iwq - iwk + 6);
  biasT[idx] = rpb[ridx * NHEADS + head];
}

// ---------------- K0c: LN1 + shift-roll + window gather -> xnw[widx][112][96] bf16 ----------------
__global__ __launch_bounds__(256) void ln1_kernel(
    const float* __restrict__ x, const float* __restrict__ g1, const float* __restrict__ b1,
    u16* __restrict__ xnw)
{
  const int tid = threadIdx.x;
  const int row = blockIdx.x * 64 + (tid >> 2);   // 0 .. NWIN*112-1
  const int qd = tid & 3;                          // quarter: 24 channels
  const int widx = row / 112;
  const int n = row - widx * 112;
  u16* dst = xnw + (size_t)row * CC + qd * 24;
  if (n >= NN) {                                   // pad row -> zeros
    uint4 z = {0u, 0u, 0u, 0u};
    *(uint4*)(dst) = z; *(uint4*)(dst + 8) = z; *(uint4*)(dst + 16) = z;
    return;
  }
  int it = n / 49, r = n - it * 49, ih = r / 7, iw = r - ih * 7;
  int ww = widx & 15, hw = (widx >> 4) & 15, tw = widx >> 8;
  int t = tw * 2 + it + 1; if (t >= TT) t -= TT;
  int h = hw * 7 + ih + 3; if (h >= HH) h -= HH;
  int w = ww * 7 + iw + 3; if (w >= WD) w -= WD;
  const float* src = x + ((size_t)(t * HH + h) * WD + w) * CC + qd * 24;
  float v[24];
  #pragma unroll
  for (int i = 0; i < 24; i += 4) {
    float4 f = *(const float4*)(src + i);
    v[i] = f.x; v[i + 1] = f.y; v[i + 2] = f.z; v[i + 3] = f.w;
  }
  float sm = 0.f;
  #pragma unroll
  for (int i = 0; i < 24; ++i) sm += v[i];
  sm += __shfl_xor(sm, 1, 64);
  sm += __shfl_xor(sm, 2, 64);
  float mu = sm * (1.f / CC);
  float sq = 0.f;
  #pragma unroll
  for (int i = 0; i < 24; ++i) { float d = v[i] - mu; sq += d * d; }
  sq += __shfl_xor(sq, 1, 64);
  sq += __shfl_xor(sq, 2, 64);
  float inv = rsqrtf(sq * (1.f / CC) + 1e-5f);
  u16 o[24];
  #pragma unroll
  for (int i = 0; i < 24; ++i) {
    int c = qd * 24 + i;
    o[i] = f2bf((v[i] - mu) * inv * g1[c] + b1[c]);
  }
  *(uint4*)(dst)      = *(const uint4*)(o);
  *(uint4*)(dst + 8)  = *(const uint4*)(o + 8);
  *(uint4*)(dst + 16) = *(const uint4*)(o + 16);
}

// ---------------- K1: per-(window,head) QKV + attention (MFMA) ----------------
__global__ __launch_bounds__(256, 4) void attn_kernel(
    const u16* __restrict__ xnw, const u16* __restrict__ qkv_wT, const float* __restrict__ qkv_b,
    const float* __restrict__ biasT, u16* __restrict__ att)
{
  // union buffer: phases 1-2 -> sQ[112][40] + sK[112][40]; phases 3-4 -> sP[112][136]
  __shared__ __align__(16) u16 sUni[112 * SVP];   // 30464 B
  __shared__ __align__(16) u16 sVt[32 * SVP];     //  8704 B  [d][kv]
  __shared__ int sReg[112];

  u16* sQ = sUni;
  u16* sK = sUni + 112 * SQP;
  u16* sP = sUni;

  const int tid  = threadIdx.x;
  const int bid  = blockIdx.x;
  const int widx = bid / 3;
  const int head = bid - widx * 3;
  const int ww = widx & 15, hw = (widx >> 4) & 15, tw = widx >> 8;
  const bool bnd = (tw == 7) || (hw == 15) || (ww == 15);
  const int wid = tid >> 6;          // wave 0..3
  const int lane = tid & 63;
  const int g  = lane >> 4;          // lane group 0..3
  const int cl = lane & 15;          // col-in-tile

  // ---- phase 0: zero sVt (pad kv cols must be 0) + region ids
  for (int i = tid; i < 32 * SVP / 2; i += 256) ((u32*)sVt)[i] = 0;
  if (tid < 112) {
    int n = tid;
    int reg = 0;
    if (n < NN) {
      int it = n / 49, r = n - it * 49, ih = r / 7, iw = r - ih * 7;
      int ts = tw * 2 + it, hs = hw * 7 + ih, ws2 = ww * 7 + iw;
      int rt = ts < TT - 2 ? 0 : (ts < TT - 1 ? 1 : 2);
      int rh = hs < HH - 7 ? 0 : (hs < HH - 3 ? 1 : 2);
      int rw = ws2 < WD - 7 ? 0 : (ws2 < WD - 3 ? 1 : 2);
      reg = rt * 9 + rh * 3 + rw;
    }
    sReg[n] = reg;
  }
  __syncthreads();

  // ---- phase 1: QKV slice for this head (A-frags straight from global; D -> sQ/sK/sVt)
  {
    const float scale = 0.17677669529663687f;   // 32^-0.5
    #pragma unroll
    for (int mi = 0; mi < 2; ++mi) {
      const int mt = wid + mi * 4;
      if (mt < 7) {
        const u16* arow = xnw + ((size_t)widx * 112 + mt * 16 + cl) * CC + 8 * g;
        bf16x8 a0 = *(const bf16x8*)(arow);
        bf16x8 a1 = *(const bf16x8*)(arow + 32);
        bf16x8 a2 = *(const bf16x8*)(arow + 64);
        #pragma unroll
        for (int nt = 0; nt < 6; ++nt) {
          const int sec = nt >> 1;                      // 0=Q 1=K 2=V
          const int col = sec * 96 + head * 32 + (nt & 1) * 16 + cl;
          const u16* brow = qkv_wT + (size_t)col * CC + 8 * g;
          f32x4 acc = {0.f, 0.f, 0.f, 0.f};
          acc = MFMA16(a0, *(const bf16x8*)(brow), acc);
          acc = MFMA16(a1, *(const bf16x8*)(brow + 32), acc);
          acc = MFMA16(a2, *(const bf16x8*)(brow + 64), acc);
          const float bias = qkv_b[col];
          #pragma unroll
          for (int r = 0; r < 4; ++r) {
            const int row = mt * 16 + 4 * g + r;
            const float v = acc[r] + bias;
            if (sec == 0)      sQ[row * SQP + (nt & 1) * 16 + cl] = f2bf(v * scale);
            else if (sec == 1) sK[row * SQP + (nt & 1) * 16 + cl] = f2bf(v);
            else               sVt[((nt & 1) * 16 + cl) * SVP + row] = f2bf(v);
          }
        }
      }
    }
  }
  __syncthreads();

  // ---- phase 2: QK^T (MFMA, K=32) + bias/mask + in-register softmax
  float sv[2][7][4];
  #pragma unroll
  for (int mi = 0; mi < 2; ++mi) {
    const int mt = wid + mi * 4;
    if (mt >= 7) continue;
    bf16x8 a = *(const bf16x8*)&sQ[(mt * 16 + cl) * SQP + 8 * g];
    #pragma unroll
    for (int nt = 0; nt < 7; ++nt) {
      bf16x8 b = *(const bf16x8*)&sK[(nt * 16 + cl) * SQP + 8 * g];
      f32x4 acc = {0.f, 0.f, 0.f, 0.f};
      acc = MFMA16(a, b, acc);
      #pragma unroll
      for (int r = 0; r < 4; ++r) sv[mi][nt][r] = acc[r];
    }
    const int q0 = mt * 16 + 4 * g;
    #pragma unroll
    for (int nt = 0; nt < 7; ++nt) {
      const int kv = nt * 16 + cl;
      #pragma unroll
      for (int r = 0; r < 4; ++r) {
        const int q = q0 + r;
        float v = sv[mi][nt][r];
        if (kv < NN) {
          if (q < NN) {
            v += biasT[((head * NN + q)) * NN + kv];
            if (bnd && sReg[q] != sReg[kv]) v -= 100.f;
          }
        } else {
          v = -1e30f;
        }
        sv[mi][nt][r] = v;
      }
    }
    #pragma unroll
    for (int r = 0; r < 4; ++r) {
      float mx = sv[mi][0][r];
      #pragma unroll
      for (int nt = 1; nt < 7; ++nt) mx = fmaxf(mx, sv[mi][nt][r]);
      #pragma unroll
      for (int d = 1; d < 16; d <<= 1) mx = fmaxf(mx, __shfl_xor(mx, d, 64));
      float sm = 0.f;
      #pragma unroll
      for (int nt = 0; nt < 7; ++nt) { float p = __expf(sv[mi][nt][r] - mx); sv[mi][nt][r] = p; sm += p; }
      #pragma unroll
      for (int d = 1; d < 16; d <<= 1) sm += __shfl_xor(sm, d, 64);
      const float inv = 1.f / sm;
      #pragma unroll
      for (int nt = 0; nt < 7; ++nt) sv[mi][nt][r] *= inv;
    }
  }
  __syncthreads();   // all Q/K reads complete before P overwrites the union buffer

  // ---- phase 3: write P (bf16) + zero pad cols 112..127
  #pragma unroll
  for (int mi = 0; mi < 2; ++mi) {
    const int mt = wid + mi * 4;
    if (mt >= 7) continue;
    #pragma unroll
    for (int r = 0; r < 4; ++r) {
      const int q = mt * 16 + 4 * g + r;
      u16* prow = &sP[q * SVP];
      #pragma unroll
      for (int nt = 0; nt < 7; ++nt) prow[nt * 16 + cl] = f2bf(sv[mi][nt][r]);
      prow[112 + cl] = 0;
    }
  }
  __syncthreads();

  // ---- phase 4: PV (MFMA, K=128) + store
  for (int t = wid; t < 14; t += 4) {
    const int mt = t >> 1, ntd = t & 1;
    f32x4 acc = {0.f, 0.f, 0.f, 0.f};
    #pragma unroll
    for (int ks = 0; ks < 4; ++ks) {
      bf16x8 a = *(const bf16x8*)&sP[(mt * 16 + cl) * SVP + ks * 32 + 8 * g];
      bf16x8 b = *(const bf16x8*)&sVt[(ntd * 16 + cl) * SVP + ks * 32 + 8 * g];
      acc = MFMA16(a, b, acc);
    }
    #pragma unroll
    for (int r = 0; r < 4; ++r) {
      const int q = mt * 16 + 4 * g + r;
      if (q < NN)
        att[((size_t)widx * NN + q) * CC + head * 32 + ntd * 16 + cl] = f2bf(acc[r]);
    }
  }
}

// ---------------- K2: fused proj + residual + LN2 + FC1 + GELU + FC2 + residual ----------------
// 32 window-tokens per block; x1 lives in registers; no x1 global buffer.
__global__ __launch_bounds__(256, 4) void pm_kernel(
    const u16* __restrict__ att, const u16* __restrict__ proj_wT, const float* __restrict__ proj_b,
    const float* __restrict__ x,
    const float* __restrict__ g2, const float* __restrict__ b2,
    const u16* __restrict__ fc1_wT, const float* __restrict__ fc1_b,
    const u16* __restrict__ fc2_wT, const float* __restrict__ fc2_b,
    float* __restrict__ out)
{
  __shared__ __align__(16) u16 sH [32 * SH2P];   // 12800 B; first 6656 B doubles as sA
  __shared__ __align__(16) u16 sX1[32 * SX1P];   //  6400 B (bf16 copy of x1 for LN2)
  __shared__ __align__(16) u16 sXn[32 * SXP];    //  6656 B
  __shared__ u32 sRowT[32];

  u16* sA = sH;   // [32][SXP] attention-output tile

  const int tid  = threadIdx.x;
  const int base = blockIdx.x * 32;              // window-token base
  const int wid = tid >> 6, lane = tid & 63, g = lane >> 4, cl = lane & 15;
  const int mt  = wid & 1;          // m-tile (16 tokens)
  const int hnt = wid >> 1;         // nt-range half

  // ---- P0: natural-row table + att tile load
  if (tid < 32) {
    int tok = base + tid;
    int widx = tok / NN, n = tok - widx * NN;
    int ww = widx & 15, hw = (widx >> 4) & 15, tw = widx >> 8;
    int it = n / 49, rr = n - it * 49, ih = rr / 7, iw = rr - ih * 7;
    int t = tw * 2 + it + 1; if (t >= TT) t -= TT;
    int h = hw * 7 + ih + 3; if (h >= HH) h -= HH;
    int w = ww * 7 + iw + 3; if (w >= WD) w -= WD;
    sRowT[tid] = (u32)((t * HH + h) * WD + w);
  }
  for (int e = tid; e < 32 * 12; e += 256) {
    int tok = e / 12, kb = e - tok * 12;
    *(uint4*)&sA[tok * SXP + kb * 8] =
        ((const uint4*)att)[(size_t)(base + tok) * 12 + kb];
  }
  __syncthreads();

  // ---- P1: proj GEMM [32x96]@[96x96] + x residual -> x1 regs + sX1 (bf16)
  float x1v[3][4];
  u32 nr0, nr1, nr2, nr3;
  {
    const u16* aRow = &sA[(mt * 16 + cl) * SXP + 8 * g];
    bf16x8 a0 = *(const bf16x8*)(aRow);
    bf16x8 a1 = *(const bf16x8*)(aRow + 32);
    bf16x8 a2 = *(const bf16x8*)(aRow + 64);
    nr0 = sRowT[mt * 16 + 4 * g + 0];
    nr1 = sRowT[mt * 16 + 4 * g + 1];
    nr2 = sRowT[mt * 16 + 4 * g + 2];
    nr3 = sRowT[mt * 16 + 4 * g + 3];
    const u32 nr[4] = {nr0, nr1, nr2, nr3};
    #pragma unroll
    for (int j = 0; j < 3; ++j) {
      const int nt = hnt * 3 + j;
      const u16* bRow = proj_wT + (nt * 16 + cl) * CC + 8 * g;
      f32x4 acc = {0.f, 0.f, 0.f, 0.f};
      acc = MFMA16(a0, *(const bf16x8*)(bRow), acc);
      acc = MFMA16(a1, *(const bf16x8*)(bRow + 32), acc);
      acc = MFMA16(a2, *(const bf16x8*)(bRow + 64), acc);
      const float bc = proj_b[nt * 16 + cl];
      #pragma unroll
      for (int r = 0; r < 4; ++r) {
        const int row = mt * 16 + 4 * g + r;
        const float v = acc[r] + bc + x[(size_t)nr[r] * CC + nt * 16 + cl];
        x1v[j][r] = v;
        sX1[row * SX1P + nt * 16 + cl] = f2bf(v);
      }
    }
  }
  __syncthreads();

  // ---- P2: LN2 from sX1 (bf16): token = tid>>3, sub = tid&7 (12 ch); 8-lane shfl reduce
  {
    const int tok = tid >> 3, sub = tid & 7;
    const u16* p = &sX1[tok * SX1P + sub * 12];
    float v[12];
    #pragma unroll
    for (int k = 0; k < 6; ++k) {
      u32 u = *(const u32*)(p + 2 * k);
      v[2 * k] = bflo(u); v[2 * k + 1] = bfhi(u);
    }
    float sm = 0.f;
    #pragma unroll
    for (int i = 0; i < 12; ++i) sm += v[i];
    sm += __shfl_xor(sm, 1, 64);
    sm += __shfl_xor(sm, 2, 64);
    sm += __shfl_xor(sm, 4, 64);
    float mu = sm * (1.f / CC);
    float sq = 0.f;
    #pragma unroll
    for (int i = 0; i < 12; ++i) { float d = v[i] - mu; sq += d * d; }
    sq += __shfl_xor(sq, 1, 64);
    sq += __shfl_xor(sq, 2, 64);
    sq += __shfl_xor(sq, 4, 64);
    float inv = rsqrtf(sq * (1.f / CC) + 1e-5f);
    u16 o[12];
    #pragma unroll
    for (int i = 0; i < 12; ++i) {
      int c = sub * 12 + i;
      o[i] = f2bf((v[i] - mu) * inv * g2[c] + b2[c]);
    }
    u16* dst = &sXn[tok * SXP + sub * 12];
    *(uint2*)(dst)     = *(const uint2*)(o);
    *(uint2*)(dst + 4) = *(const uint2*)(o + 4);
    *(uint2*)(dst + 8) = *(const uint2*)(o + 8);
  }
  __syncthreads();

  // ---- P3/P4: two halves of FC1(+GELU) -> sH(192 cols), FC2 partial-k accumulate
  f32x4 acc2[3];
  #pragma unroll
  for (int j = 0; j < 3; ++j) { f32x4 z = {0.f, 0.f, 0.f, 0.f}; acc2[j] = z; }

  const u16* aXn = &sXn[(mt * 16 + cl) * SXP + 8 * g];
  bf16x8 xa0 = *(const bf16x8*)(aXn);
  bf16x8 xa1 = *(const bf16x8*)(aXn + 32);
  bf16x8 xa2 = *(const bf16x8*)(aXn + 64);

  #pragma unroll
  for (int hf = 0; hf < 2; ++hf) {
    // GEMM1 half: 6 nt per wave
    {
      const int ntg0 = hf * 12 + hnt * 6;
      const u16* bPtr = fc1_wT + ((size_t)(ntg0 * 16 + cl)) * CC + 8 * g;
      bf16x8 b0 = *(const bf16x8*)(bPtr);
      bf16x8 b1 = *(const bf16x8*)(bPtr + 32);
      bf16x8 b2 = *(const bf16x8*)(bPtr + 64);
      #pragma unroll
      for (int j = 0; j < 6; ++j) {
        bf16x8 c0 = b0, c1 = b1, c2 = b2;
        if (j < 5) {
          bPtr += 16 * CC;
          b0 = *(const bf16x8*)(bPtr);
          b1 = *(const bf16x8*)(bPtr + 32);
          b2 = *(const bf16x8*)(bPtr + 64);
        }
        f32x4 acc = {0.f, 0.f, 0.f, 0.f};
        acc = MFMA16(xa0, c0, acc);
        acc = MFMA16(xa1, c1, acc);
        acc = MFMA16(xa2, c2, acc);
        const int ntg = ntg0 + j;
        const float bj = fc1_b[ntg * 16 + cl];
        #pragma unroll
        for (int r = 0; r < 4; ++r) {
          float v = acc[r] + bj;
          // tanh-GELU: v*e/(e+1), e = exp(v*(1.59576912 + 0.07135481*v^2))
          float p2 = v * v;
          float a  = v * fmaf(0.07135481f, p2, 1.59576912f);
          float e  = __expf(a);
          float gl = v * e * __builtin_amdgcn_rcpf(e + 1.f);
          sH[(mt * 16 + 4 * g + r) * SH2P + (hnt * 6 + j) * 16 + cl] = f2bf(gl);
        }
      }
    }
    __syncthreads();
    // GEMM2 partial: k-slices hf*192..+192
    {
      const u16* aBase = &sH[(mt * 16 + cl) * SH2P + 8 * g];
      bf16x8 a[6];
      #pragma unroll
      for (int ks = 0; ks < 6; ++ks) a[ks] = *(const bf16x8*)(aBase + 32 * ks);
      #pragma unroll
      for (int j = 0; j < 3; ++j) {
        const int nt = hnt * 3 + j;
        const u16* bBase = fc2_wT + (size_t)(nt * 16 + cl) * MLPH + hf * 192 + 8 * g;
        #pragma unroll
        for (int ks = 0; ks < 6; ++ks)
          acc2[j] = MFMA16(a[ks], *(const bf16x8*)(bBase + 32 * ks), acc2[j]);
      }
    }
    __syncthreads();
  }

  // ---- epilogue: out = x1(reg) + fc2_b + acc2
  {
    const u32 nr[4] = {nr0, nr1, nr2, nr3};
    #pragma unroll
    for (int j = 0; j < 3; ++j) {
      const int nt = hnt * 3 + j;
      const float bc = fc2_b[nt * 16 + cl];
      #pragma unroll
      for (int r = 0; r < 4; ++r) {
        out[(size_t)nr[r] * CC + nt * 16 + cl] = x1v[j][r] + acc2[j][r] + bc;
      }
    }
  }
}

extern "C" void kernel_launch(void* const* d_in, const int* in_sizes, int n_in,
                              void* d_out, int out_size, void* d_ws, size_t ws_size,
                              hipStream_t stream) {
  const float* x      = (const float*)d_in[0];
  const float* g1     = (const float*)d_in[1];
  const float* b1     = (const float*)d_in[2];
  const float* qkv_w  = (const float*)d_in[3];
  const float* qkv_b  = (const float*)d_in[4];
  const float* rpb    = (const float*)d_in[5];
  const float* proj_w = (const float*)d_in[6];
  const float* proj_b = (const float*)d_in[7];
  const float* g2     = (const float*)d_in[8];
  const float* b2     = (const float*)d_in[9];
  const float* fc1_w  = (const float*)d_in[10];
  const float* fc1_b  = (const float*)d_in[11];
  const float* fc2_w  = (const float*)d_in[12];
  const float* fc2_b  = (const float*)d_in[13];

  char* ws = (char*)d_ws;
  u16*   att    = (u16*)ws;                                   // NTOK*96 bf16 = 38.5 MB
  u16*   xnw    = (u16*)(ws + (size_t)NTOK * CC * 2);         // NWIN*112*96 bf16 = 44 MB
  char*  wtail  = ws + (size_t)NTOK * CC * 2 + (size_t)NWIN * 112 * CC * 2;
  float* biasT  = (float*)wtail;                              // 115248 B
  u16*   qkv_wT = (u16*)(wtail + 115248);                     // 55296 B
  u16*   proj_wT= (u16*)(wtail + 115248 + 55296);             // 18432 B
  u16*   fc1_wT = (u16*)(wtail + 115248 + 55296 + 18432);     // 73728 B
  u16*   fc2_wT = (u16*)(wtail + 115248 + 55296 + 18432 + 73728); // 73728 B

  wprep_kernel<<<(27648 + 9216 + 36864 + 36864 + 255) / 256, 256, 0, stream>>>(
      qkv_w, proj_w, fc1_w, fc2_w, qkv_wT, proj_wT, fc1_wT, fc2_wT);
  bias_kernel<<<(NHEADS * NN * NN + 255) / 256, 256, 0, stream>>>(rpb, biasT);
  ln1_kernel<<<NWIN * 112 / 64, 256, 0, stream>>>(x, g1, b1, xnw);
  attn_kernel<<<NWIN * NHEADS, 256, 0, stream>>>(xnw, qkv_wT, qkv_b, biasT, att);
  pm_kernel<<<NTOK / 32, 256, 0, stream>>>(att, proj_wT, proj_b, x, g2, b2,
                                           fc1_wT, fc1_b, fc2_wT, fc2_b, (float*)d_out);
}